// Round 2
// baseline (28844.577 us; speedup 1.0000x reference)
//
#include <hip/hip_runtime.h>
#include <math.h>

#define NB 4
#define BATCH 8
#define NF 128
#define WDIM 512
#define EPS_D 1e-8f
#define COG 8   // couts per workgroup
#define CI 8    // cin chunk

// ---------------- style: s[i][b][o] = w[i,b,:] . (to_style_w[i,o,:]*cl) + tsb[i,o]
__global__ void k_style(const float* __restrict__ w,
                        const float* __restrict__ tsw,
                        const float* __restrict__ tsb,
                        float* __restrict__ s) {
    int gid = blockIdx.x * blockDim.x + threadIdx.x; // 4096 total
    if (gid >= NB * BATCH * NF) return;
    int i = gid >> 10;
    int b = (gid >> 7) & 7;
    int o = gid & 127;
    const float cl = 0.044194173824159216f; // 1/sqrt(512)
    const float* wr = w + (i * BATCH + b) * WDIM;
    const float* tr = tsw + (i * NF + o) * WDIM;
    float acc = 0.f;
    for (int k = 0; k < WDIM; ++k) acc += wr[k] * tr[k];
    s[gid] = acc * cl + tsb[i * NF + o];
}

// ---------------- demod: d[i][j][b][o] = rsqrt(c2 * sum_c s^2 * sum_k w^2 + eps)
__global__ void k_demod(const float* __restrict__ conv_w, // [4][2][128][128][9]
                        const float* __restrict__ s,      // [4][8][128]
                        float* __restrict__ d) {          // [4][2][8][128]
    int bx = blockIdx.x; // 1024 = i*256 + j*128 + o
    int i = bx >> 8;
    int j = (bx >> 7) & 1;
    int o = bx & 127;
    int lane = threadIdx.x; // 64
    const float* wb = conv_w + (size_t)(((i * 2 + j) * NF + o) * NF) * 9;
    float t0 = 0.f, t1 = 0.f;
    for (int k = 0; k < 9; ++k) {
        float a = wb[lane * 9 + k];        t0 += a * a;
        float c = wb[(lane + 64) * 9 + k]; t1 += c * c;
    }
    const float c2 = 1.0f / 1152.0f; // (1/sqrt(128*9))^2
    for (int b = 0; b < BATCH; ++b) {
        float s0 = s[(i * BATCH + b) * NF + lane];
        float s1 = s[(i * BATCH + b) * NF + lane + 64];
        float v = t0 * s0 * s0 + t1 * s1 * s1;
        for (int off = 32; off > 0; off >>= 1) v += __shfl_down(v, off);
        if (lane == 0) d[((i * 2 + j) * BATCH + b) * NF + o] = rsqrtf(v * c2 + EPS_D);
    }
}

// ---------------- initial constant, relu, replicated for g samples
__global__ void k_init(const float* __restrict__ ic, float* __restrict__ x, int total) {
    for (int idx = blockIdx.x * blockDim.x + threadIdx.x; idx < total;
         idx += gridDim.x * blockDim.x) {
        int cp = idx & (NF * 32 * 32 - 1); // 131072 per sample
        float v = ic[cp];
        x[idx] = v > 0.f ? v : 0.f;
    }
}

// ---------------- 2x bilinear upsample (half-pixel centers, clamp == renorm)
__global__ void k_up2(const float* __restrict__ in, float* __restrict__ out,
                      int h, int w, int total) {
    int W2 = 2 * w, H2 = 2 * h;
    for (int idx = blockIdx.x * blockDim.x + threadIdx.x; idx < total;
         idx += gridDim.x * blockDim.x) {
        int ox = idx % W2;
        int t = idx / W2;
        int oy = t % H2;
        int bc = t / H2;
        int y0 = (oy >> 1) - 1 + (oy & 1);
        float wy0 = (oy & 1) ? 0.75f : 0.25f;
        int x0 = (ox >> 1) - 1 + (ox & 1);
        float wx0 = (ox & 1) ? 0.75f : 0.25f;
        int y1 = y0 + 1, x1 = x0 + 1;
        y0 = max(y0, 0); y1 = min(y1, h - 1);
        x0 = max(x0, 0); x1 = min(x1, w - 1);
        const float* p = in + (size_t)bc * h * w;
        float v00 = p[y0 * w + x0], v01 = p[y0 * w + x1];
        float v10 = p[y1 * w + x0], v11 = p[y1 * w + x1];
        float wy1 = 1.f - wy0, wx1 = 1.f - wx0;
        out[idx] = wy0 * (wx0 * v00 + wx1 * v01) + wy1 * (wx0 * v10 + wx1 * v11);
    }
}

// ---------------- modulated 3x3 conv + demod + noise + bias + leaky_relu
// 32x32 pixel tile x COG couts per WG; 256 thr: each 2x2 px x 8 couts.
// blockIdx.z = local sample (in group); global sample = b0 + z.
__global__ __launch_bounds__(256) void k_conv(
    const float* __restrict__ x, float* __restrict__ y,
    const float* __restrict__ wconv,   // [128][128][9] for this (i,j)
    const float* __restrict__ s_b,     // [8][128] block i (global batch)
    const float* __restrict__ d_b,     // [8][128] (i,j)  (global batch)
    const float* __restrict__ noise,   // [8][H][W] (global batch)
    const float* __restrict__ bias,    // [128] (i,j)
    const float* __restrict__ sn_ptr,  // scalar on device
    int H, int W, int b0)
{
    __shared__ float in_t[CI * 34 * 34];
    __shared__ float w_t[COG * CI * 9];
    int tid = threadIdx.x;
    int zb = blockIdx.z;
    int b = b0 + zb;
    int cobase = blockIdx.y * COG;
    int tilesX = W >> 5;
    int tx0 = (blockIdx.x % tilesX) << 5;
    int ty0 = (blockIdx.x / tilesX) << 5;
    const float cscale = 0.029462782549439483f; // 1/sqrt(1152)
    const float* sb = s_b + b * NF;

    float acc[COG][4];
    #pragma unroll
    for (int co = 0; co < COG; ++co)
        #pragma unroll
        for (int p = 0; p < 4; ++p) acc[co][p] = 0.f;

    int tyy = tid >> 4;  // 0..15
    int txx = tid & 15;

    for (int cb = 0; cb < NF; cb += CI) {
        __syncthreads();
        for (int idx = tid; idx < CI * 34 * 34; idx += 256) {
            int ci = idx / 1156;
            int r = idx - ci * 1156;
            int yy = r / 34;
            int xx = r - yy * 34;
            int gy = ty0 + yy - 1;
            int gx = tx0 + xx - 1;
            float v = 0.f;
            if ((unsigned)gy < (unsigned)H && (unsigned)gx < (unsigned)W)
                v = x[((size_t)(zb * NF + cb + ci) * H + gy) * W + gx] * sb[cb + ci];
            in_t[idx] = v;
        }
        for (int idx = tid; idx < COG * CI * 9; idx += 256) {
            int co = idx / (CI * 9);
            int r = idx - co * (CI * 9);
            int ci = r / 9;
            int k = r - ci * 9;
            w_t[idx] = wconv[((cobase + co) * NF + cb + ci) * 9 + k] * cscale;
        }
        __syncthreads();
        #pragma unroll
        for (int ci = 0; ci < CI; ++ci) {
            float n[4][4];
            const float* ip = in_t + ci * 1156 + (2 * tyy) * 34 + 2 * txx;
            #pragma unroll
            for (int r = 0; r < 4; ++r)
                #pragma unroll
                for (int c = 0; c < 4; ++c)
                    n[r][c] = ip[r * 34 + c];
            #pragma unroll
            for (int co = 0; co < COG; ++co) {
                const float* wp = w_t + (co * CI + ci) * 9;
                float w0 = wp[0], w1 = wp[1], w2 = wp[2], w3 = wp[3], w4 = wp[4];
                float w5 = wp[5], w6 = wp[6], w7 = wp[7], w8 = wp[8];
                #pragma unroll
                for (int dy = 0; dy < 2; ++dy)
                    #pragma unroll
                    for (int dx = 0; dx < 2; ++dx) {
                        float a = acc[co][dy * 2 + dx];
                        a += w0 * n[dy + 0][dx + 0] + w1 * n[dy + 0][dx + 1] + w2 * n[dy + 0][dx + 2];
                        a += w3 * n[dy + 1][dx + 0] + w4 * n[dy + 1][dx + 1] + w5 * n[dy + 1][dx + 2];
                        a += w6 * n[dy + 2][dx + 0] + w7 * n[dy + 2][dx + 1] + w8 * n[dy + 2][dx + 2];
                        acc[co][dy * 2 + dx] = a;
                    }
            }
        }
    }
    float sn = sn_ptr[0];
    #pragma unroll
    for (int co = 0; co < COG; ++co) {
        float dd = d_b[b * NF + cobase + co];
        float bb = bias[cobase + co];
        #pragma unroll
        for (int dy = 0; dy < 2; ++dy)
            #pragma unroll
            for (int dx = 0; dx < 2; ++dx) {
                int py = ty0 + 2 * tyy + dy;
                int px = tx0 + 2 * txx + dx;
                float nv = noise[((size_t)b * H + py) * W + px];
                float v = acc[co][dy * 2 + dx] * dd + sn * nv + bb;
                y[((size_t)(zb * NF + cobase + co) * H + py) * W + px] = v > 0.f ? v : 0.2f * v;
            }
    }
}

// ---------------- ToRGB (1x1 conv to 1 channel, no demod)
// blockIdx.y = local sample; rgb written at GLOBAL sample offset.
__global__ void k_rgb(const float* __restrict__ x, float* __restrict__ rgb,
                      const float* __restrict__ rgbw, // [128] block i
                      const float* __restrict__ s_b,  // [8][128] (global)
                      int HW, int b0)
{
    __shared__ float coeff[NF];
    int zb = blockIdx.y;
    int b = b0 + zb;
    if (threadIdx.x < NF)
        coeff[threadIdx.x] = rgbw[threadIdx.x] * 0.08838834764831845f /*1/sqrt(128)*/
                             * s_b[b * NF + threadIdx.x];
    __syncthreads();
    for (int p = blockIdx.x * blockDim.x + threadIdx.x; p < HW;
         p += gridDim.x * blockDim.x) {
        float acc = 0.f;
        const float* xp = x + (size_t)zb * NF * HW + p;
        #pragma unroll 4
        for (int c = 0; c < NF; ++c) acc += xp[(size_t)c * HW] * coeff[c];
        rgb[(size_t)b * HW + p] = acc;
    }
}

// ---------------- bilinear upsample rgb (r->256) and accumulate (group slice)
__global__ void k_rgbacc(const float* __restrict__ rgb, float* __restrict__ acc,
                         int r, int beta, int b0, int g) {
    int idx = blockIdx.x * blockDim.x + threadIdx.x;
    if (idx >= g * 256 * 256) return;
    int ox = idx & 255;
    int oy = (idx >> 8) & 255;
    int b = b0 + (idx >> 16);
    float scale = (float)r * (1.0f / 256.0f);
    float fy = (oy + 0.5f) * scale - 0.5f;
    float fx = (ox + 0.5f) * scale - 0.5f;
    int y0 = (int)floorf(fy); float wy = fy - (float)y0;
    int x0 = (int)floorf(fx); float wx = fx - (float)x0;
    int y1 = min(y0 + 1, r - 1); y0 = max(y0, 0);
    int x1 = min(x0 + 1, r - 1); x0 = max(x0, 0);
    const float* p = rgb + (size_t)b * r * r;
    float v = (1.f - wy) * ((1.f - wx) * p[y0 * r + x0] + wx * p[y0 * r + x1])
            +        wy  * ((1.f - wx) * p[y1 * r + x0] + wx * p[y1 * r + x1]);
    int oidx = (b << 16) | (oy << 8) | ox;
    acc[oidx] = (beta ? acc[oidx] : 0.f) + v;
}

__global__ void k_final(const float* __restrict__ acc, float* __restrict__ out, int total) {
    int idx = blockIdx.x * blockDim.x + threadIdx.x;
    if (idx < total) out[idx] = acc[idx] * 0.5f + 0.5f;
}

extern "C" void kernel_launch(void* const* d_in, const int* in_sizes, int n_in,
                              void* d_out, int out_size, void* d_ws, size_t ws_size,
                              hipStream_t stream) {
    const float* w     = (const float*)d_in[0];
    const float* noise[4] = {(const float*)d_in[1], (const float*)d_in[2],
                             (const float*)d_in[3], (const float*)d_in[4]};
    const float* ic    = (const float*)d_in[5];
    const float* tsw   = (const float*)d_in[6];
    const float* tsb   = (const float*)d_in[7];
    const float* cw    = (const float*)d_in[8];
    const float* snp   = (const float*)d_in[9];
    const float* sbias = (const float*)d_in[10];
    const float* rgbw  = (const float*)d_in[11];

    // ---- adaptive workspace: process batch in groups of g samples ----
    // fixed region: s(16K) + d(32K) + acc(2M) + rgb(2M) = 4,243,456 B
    // per-group ping-pong: 2 * g * 128*256*256*4 = g * 67,108,864 B
    const size_t FIXED = 16384 + 32768 + 2097152 + 2097152;
    int g = 0;
    for (int cand = 8; cand >= 1; cand >>= 1)
        if (ws_size >= FIXED + (size_t)cand * 67108864ull) { g = cand; break; }
    if (g == 0) return; // ws_size < 71.4 MB: cannot run (diagnostic: zeros)

    char* ws = (char*)d_ws;
    float* s_all = (float*)ws;
    float* d_all = (float*)(ws + 16384);
    float* accb  = (float*)(ws + 49152);
    float* rgbb  = (float*)(ws + 49152 + 2097152);
    float* bufA  = (float*)(ws + FIXED);
    float* bufB  = (float*)(ws + FIXED + (size_t)g * 33554432ull);

    k_style<<<64, 64, 0, stream>>>(w, tsw, tsb, s_all);
    k_demod<<<1024, 64, 0, stream>>>(cw, s_all, d_all);

    for (int b0 = 0; b0 < BATCH; b0 += g) {
        float* xb = bufA;
        float* tb = bufB;
        k_init<<<1024, 256, 0, stream>>>(ic, xb, g * NF * 32 * 32);
        for (int i = 0; i < NB; ++i) {
            int r = 32 << i;
            if (i > 0) {
                int total = g * NF * r * r;
                int blocks = (total + 255) / 256;
                if (blocks > 4096) blocks = 4096;
                k_up2<<<blocks, 256, 0, stream>>>(xb, tb, r / 2, r / 2, total);
                float* tmp = xb; xb = tb; tb = tmp;
            }
            const float* s_i = s_all + i * BATCH * NF;
            for (int j = 0; j < 2; ++j) {
                const float* wij = cw + (size_t)((i * 2 + j) * NF * NF) * 9;
                const float* dij = d_all + (i * 2 + j) * BATCH * NF;
                const float* nz  = noise[i] + (size_t)j * BATCH * r * r;
                const float* bs  = sbias + (i * 2 + j) * NF;
                dim3 grid((r / 32) * (r / 32), NF / COG, g);
                k_conv<<<grid, 256, 0, stream>>>(xb, tb, wij, s_i, dij, nz, bs,
                                                 snp + i * 2 + j, r, r, b0);
                float* tmp = xb; xb = tb; tb = tmp;
            }
            int HW = r * r;
            int bx = (HW + 255) / 256;
            if (bx > 1024) bx = 1024;
            dim3 rgrid(bx, g);
            k_rgb<<<rgrid, 256, 0, stream>>>(xb, rgbb, rgbw + i * NF, s_i, HW, b0);
            int tot = g * 256 * 256;
            k_rgbacc<<<(tot + 255) / 256, 256, 0, stream>>>(rgbb, accb, r, i, b0, g);
        }
    }
    k_final<<<(out_size + 255) / 256, 256, 0, stream>>>(accb, (float*)d_out, out_size);
}

// Round 3
// 1986.211 us; speedup vs baseline: 14.5224x; 14.5224x over previous
//
#include <hip/hip_runtime.h>
#include <math.h>

#define NB 4
#define BATCH 8
#define NF 128
#define WDIM 512
#define EPS_D 1e-8f

typedef unsigned short ushortT;
typedef __attribute__((ext_vector_type(8))) short short8v;
typedef __attribute__((ext_vector_type(8))) unsigned short ushort8v;
typedef __attribute__((ext_vector_type(4))) float float4v;
typedef __attribute__((ext_vector_type(4))) unsigned int uint4v;

__device__ inline unsigned short f2bf(float f) {
    unsigned u = __builtin_bit_cast(unsigned, f);
    u = (u + 0x7fffu + ((u >> 16) & 1u)) >> 16;
    return (unsigned short)u;
}
__device__ inline float bf2f(unsigned short h) {
    unsigned u = ((unsigned)h) << 16;
    return __builtin_bit_cast(float, u);
}

// ---------------- style: s[i][b][o] = w[i,b,:] . (to_style_w[i,o,:]*cl) + tsb[i,o]
__global__ void k_style(const float* __restrict__ w,
                        const float* __restrict__ tsw,
                        const float* __restrict__ tsb,
                        float* __restrict__ s) {
    int gid = blockIdx.x * blockDim.x + threadIdx.x;
    if (gid >= NB * BATCH * NF) return;
    int i = gid >> 10;
    int b = (gid >> 7) & 7;
    int o = gid & 127;
    const float cl = 0.044194173824159216f; // 1/sqrt(512)
    const float* wr = w + (i * BATCH + b) * WDIM;
    const float* tr = tsw + (i * NF + o) * WDIM;
    float acc = 0.f;
    for (int k = 0; k < WDIM; ++k) acc += wr[k] * tr[k];
    s[gid] = acc * cl + tsb[i * NF + o];
}

// ---------------- demod (f32, exact as reference)
__global__ void k_demod(const float* __restrict__ conv_w,
                        const float* __restrict__ s,
                        float* __restrict__ d) {
    int bx = blockIdx.x; // 1024 = l*128 + o
    int l = bx >> 7;
    int o = bx & 127;
    int lane = threadIdx.x; // 64
    const float* wb = conv_w + (size_t)((l * NF + o) * NF) * 9;
    float t0 = 0.f, t1 = 0.f;
    for (int k = 0; k < 9; ++k) {
        float a = wb[lane * 9 + k];        t0 += a * a;
        float c = wb[(lane + 64) * 9 + k]; t1 += c * c;
    }
    const float c2 = 1.0f / 1152.0f;
    int i = l >> 1;
    for (int b = 0; b < BATCH; ++b) {
        float s0 = s[(i * BATCH + b) * NF + lane];
        float s1 = s[(i * BATCH + b) * NF + lane + 64];
        float v = t0 * s0 * s0 + t1 * s1 * s1;
        for (int off = 32; off > 0; off >>= 1) v += __shfl_down(v, off);
        if (lane == 0) d[(l * BATCH + b) * NF + o] = rsqrtf(v * c2 + EPS_D);
    }
}

// ---------------- per-sample modulated bf16 weights Wm[l][b][t][co][ci]
__global__ void k_wmod(const float* __restrict__ cw, const float* __restrict__ s,
                       ushortT* __restrict__ wm, int total) {
    int idx = blockIdx.x * blockDim.x + threadIdx.x;
    if (idx >= total) return;
    int ci = idx & 127;
    int co = (idx >> 7) & 127;
    int t = (idx >> 14) % 9;
    int rest = idx / (16384 * 9);
    int b = rest & 7;
    int l = rest >> 3;
    const float cscale = 0.029462782549439483f; // 1/sqrt(1152)
    float v = cw[((size_t)(l * NF + co) * NF + ci) * 9 + t] * cscale
            * s[((l >> 1) * BATCH + b) * NF + ci];
    wm[idx] = f2bf(v);
}

// ---------------- initial constant -> relu -> bf16 NHWC per group sample
__global__ void k_prep_init(const float* __restrict__ ic, ushortT* __restrict__ xp,
                            int total) {
    for (int idx = blockIdx.x * blockDim.x + threadIdx.x; idx < total;
         idx += gridDim.x * blockDim.x) {
        int ci = idx & 127;
        int p = (idx >> 7) & 1023;
        float v = ic[ci * 1024 + p];
        xp[idx] = f2bf(v > 0.f ? v : 0.f);
    }
}

// ---------------- 2x bilinear upsample, bf16 NHWC
__global__ void k_up2_bf(const ushortT* __restrict__ in, ushortT* __restrict__ out,
                         int h, int w, int total) {
    int W2 = w * 2, H2 = h * 2;
    for (int gid = blockIdx.x * blockDim.x + threadIdx.x; gid < total;
         gid += gridDim.x * blockDim.x) {
        int cg = gid & 15;
        int t = gid >> 4;
        int ox = t % W2; t /= W2;
        int oy = t % H2; int zb = t / H2;
        int y0 = (oy >> 1) - 1 + (oy & 1);
        float wy0 = (oy & 1) ? 0.75f : 0.25f;
        int x0 = (ox >> 1) - 1 + (ox & 1);
        float wx0 = (ox & 1) ? 0.75f : 0.25f;
        int y1 = min(y0 + 1, h - 1); y0 = max(y0, 0);
        int x1 = min(x0 + 1, w - 1); x0 = max(x0, 0);
        const ushortT* base = in + (size_t)zb * h * w * 128 + cg * 8;
        ushort8v v00 = *(const ushort8v*)(base + (size_t)(y0 * w + x0) * 128);
        ushort8v v01 = *(const ushort8v*)(base + (size_t)(y0 * w + x1) * 128);
        ushort8v v10 = *(const ushort8v*)(base + (size_t)(y1 * w + x0) * 128);
        ushort8v v11 = *(const ushort8v*)(base + (size_t)(y1 * w + x1) * 128);
        float wy1 = 1.f - wy0, wx1 = 1.f - wx0;
        ushort8v o;
        #pragma unroll
        for (int k = 0; k < 8; ++k) {
            float v = wy0 * (wx0 * bf2f(v00[k]) + wx1 * bf2f(v01[k]))
                    + wy1 * (wx0 * bf2f(v10[k]) + wx1 * bf2f(v11[k]));
            o[k] = f2bf(v);
        }
        *(ushort8v*)(out + ((size_t)(zb * H2 + oy) * W2 + ox) * 128 + cg * 8) = o;
    }
}

// ---------------- modulated conv3x3 via bf16 MFMA implicit GEMM
// block: 8x8 pixel tile x 128 co, 4 waves = (2 co-halves) x (2 pixel-halves)
// wave: 64 co x 32 pix; per (tap,kchunk): 4 A-frags (global), 2 B-frags (LDS), 8 MFMA
__global__ __launch_bounds__(256) void k_conv_mfma(
    const ushortT* __restrict__ xp, ushortT* __restrict__ yp,
    const ushortT* __restrict__ wl,   // [8][9][128][128] bf16 (this layer)
    const float* __restrict__ d_b,    // [8][128]
    const float* __restrict__ nz,     // [8][H][W] f32
    const float* __restrict__ bias,   // [128]
    const float* __restrict__ sn_ptr,
    int H, int W, int b0)
{
    __shared__ uint4v ldsq[1600];     // 25600 B: halo 10x10 x 128ci bf16 (swizzled)
    char* lb = (char*)ldsq;
    int tid = threadIdx.x;
    int lane = tid & 63;
    int wave = tid >> 6;
    int wm = wave >> 1, wn = wave & 1;
    int lm = lane & 15, lk = lane >> 4;
    int tilesX = W >> 3;
    int tx0 = (blockIdx.x % tilesX) << 3;
    int ty0 = (blockIdx.x / tilesX) << 3;
    int zb = blockIdx.y;
    int b = b0 + zb;

    // stage halo: 100 pixels x 256B, XOR-swizzled 16B chunks
    for (int sidx = tid; sidx < 1600; sidx += 256) {
        int hp = sidx >> 4;
        int ck = sidx & 15;
        int hy = hp / 10;
        int hx = hp - hy * 10;
        int gy = ty0 + hy - 1, gx = tx0 + hx - 1;
        uint4v v = {0, 0, 0, 0};
        if ((unsigned)gy < (unsigned)H && (unsigned)gx < (unsigned)W)
            v = *(const uint4v*)(xp + (((size_t)zb * H + gy) * W + gx) * 128 + ck * 8);
        *(uint4v*)(lb + hp * 256 + ((ck << 4) ^ ((hp & 15) << 4))) = v;
    }
    __syncthreads();

    float4v acc[4][2];
    #pragma unroll
    for (int mt = 0; mt < 4; ++mt)
        #pragma unroll
        for (int nt = 0; nt < 2; ++nt)
            acc[mt][nt] = (float4v){0.f, 0.f, 0.f, 0.f};

    const ushortT* wb = wl + (size_t)b * (9 * 128 * 128);
    int p0 = wn * 32 + lm;
    int p1 = p0 + 16;
    int py0 = p0 >> 3, px0 = p0 & 7;
    int py1 = p1 >> 3, px1 = p1 & 7;
    int coA = wm * 64 + lm;
    int ciE = lk * 8;

    #pragma unroll
    for (int t = 0; t < 9; ++t) {
        int dy = t / 3, dx = t % 3;
        int hp0 = (py0 + dy) * 10 + px0 + dx;
        int hp1 = (py1 + dy) * 10 + px1 + dx;
        const ushortT* wt = wb + t * 16384;
        #pragma unroll
        for (int kk = 0; kk < 4; ++kk) {
            int cib = (kk * 32 + ciE) * 2;
            short8v bf0 = *(const short8v*)(lb + hp0 * 256 + (cib ^ ((hp0 & 15) << 4)));
            short8v bf1 = *(const short8v*)(lb + hp1 * 256 + (cib ^ ((hp1 & 15) << 4)));
            const ushortT* wr = wt + kk * 32 + ciE;
            short8v a0 = *(const short8v*)(wr + (size_t)(coA +  0) * 128);
            short8v a1 = *(const short8v*)(wr + (size_t)(coA + 16) * 128);
            short8v a2 = *(const short8v*)(wr + (size_t)(coA + 32) * 128);
            short8v a3 = *(const short8v*)(wr + (size_t)(coA + 48) * 128);
            acc[0][0] = __builtin_amdgcn_mfma_f32_16x16x32_bf16(a0, bf0, acc[0][0], 0, 0, 0);
            acc[0][1] = __builtin_amdgcn_mfma_f32_16x16x32_bf16(a0, bf1, acc[0][1], 0, 0, 0);
            acc[1][0] = __builtin_amdgcn_mfma_f32_16x16x32_bf16(a1, bf0, acc[1][0], 0, 0, 0);
            acc[1][1] = __builtin_amdgcn_mfma_f32_16x16x32_bf16(a1, bf1, acc[1][1], 0, 0, 0);
            acc[2][0] = __builtin_amdgcn_mfma_f32_16x16x32_bf16(a2, bf0, acc[2][0], 0, 0, 0);
            acc[2][1] = __builtin_amdgcn_mfma_f32_16x16x32_bf16(a2, bf1, acc[2][1], 0, 0, 0);
            acc[3][0] = __builtin_amdgcn_mfma_f32_16x16x32_bf16(a3, bf0, acc[3][0], 0, 0, 0);
            acc[3][1] = __builtin_amdgcn_mfma_f32_16x16x32_bf16(a3, bf1, acc[3][1], 0, 0, 0);
        }
    }
    __syncthreads();   // done reading halo; reuse LDS for output transpose

    float sn = sn_ptr[0];
    int pp[2] = {p0, p1};
    float nv[2];
    #pragma unroll
    for (int nt = 0; nt < 2; ++nt) {
        int gy = ty0 + (pp[nt] >> 3), gx = tx0 + (pp[nt] & 7);
        nv[nt] = sn * nz[((size_t)b * H + gy) * W + gx];
    }
    #pragma unroll
    for (int mt = 0; mt < 4; ++mt) {
        int co0 = wm * 64 + mt * 16 + lk * 4;
        float4v dd = *(const float4v*)(d_b + b * 128 + co0);
        float4v bb = *(const float4v*)(bias + co0);
        #pragma unroll
        for (int nt = 0; nt < 2; ++nt) {
            int p = pp[nt];
            unsigned pk[2];
            #pragma unroll
            for (int h = 0; h < 2; ++h) {
                float va = acc[mt][nt][2 * h]     * dd[2 * h]     + nv[nt] + bb[2 * h];
                float vb = acc[mt][nt][2 * h + 1] * dd[2 * h + 1] + nv[nt] + bb[2 * h + 1];
                va = va > 0.f ? va : 0.2f * va;
                vb = vb > 0.f ? vb : 0.2f * vb;
                pk[h] = (unsigned)f2bf(va) | ((unsigned)f2bf(vb) << 16);
            }
            int addr = p * 256 + ((co0 * 2) ^ ((p & 7) << 5));
            *(unsigned*)(lb + addr) = pk[0];
            *(unsigned*)(lb + addr + 4) = pk[1];
        }
    }
    __syncthreads();
    for (int sidx = tid; sidx < 1024; sidx += 256) {
        int p = sidx >> 4;
        int ck = sidx & 15;
        uint4v v = *(const uint4v*)(lb + p * 256 + ((ck << 4) ^ ((p & 7) << 5)));
        int gy = ty0 + (p >> 3), gx = tx0 + (p & 7);
        *(uint4v*)(yp + (((size_t)zb * H + gy) * W + gx) * 128 + ck * 8) = v;
    }
}

// ---------------- ToRGB 1x1 conv, bf16 NHWC input, f32 out
__global__ void k_rgb_bf(const ushortT* __restrict__ x, float* __restrict__ rgb,
                         const float* __restrict__ rgbw,
                         const float* __restrict__ s_b,
                         int HW, int b0)
{
    __shared__ float coeff[NF];
    int zb = blockIdx.y;
    int b = b0 + zb;
    if (threadIdx.x < NF)
        coeff[threadIdx.x] = rgbw[threadIdx.x] * 0.08838834764831845f
                             * s_b[b * NF + threadIdx.x];
    __syncthreads();
    for (int p = blockIdx.x * blockDim.x + threadIdx.x; p < HW;
         p += gridDim.x * blockDim.x) {
        const ushortT* xpr = x + ((size_t)zb * HW + p) * 128;
        float acc = 0.f;
        #pragma unroll
        for (int c = 0; c < 128; c += 8) {
            ushort8v v = *(const ushort8v*)(xpr + c);
            #pragma unroll
            for (int k = 0; k < 8; ++k) acc += bf2f(v[k]) * coeff[c + k];
        }
        rgb[(size_t)b * HW + p] = acc;
    }
}

// ---------------- bilinear upsample rgb (r->256) and accumulate (group slice)
__global__ void k_rgbacc(const float* __restrict__ rgb, float* __restrict__ acc,
                         int r, int beta, int b0, int g) {
    int idx = blockIdx.x * blockDim.x + threadIdx.x;
    if (idx >= g * 256 * 256) return;
    int ox = idx & 255;
    int oy = (idx >> 8) & 255;
    int b = b0 + (idx >> 16);
    float scale = (float)r * (1.0f / 256.0f);
    float fy = (oy + 0.5f) * scale - 0.5f;
    float fx = (ox + 0.5f) * scale - 0.5f;
    int y0 = (int)floorf(fy); float wy = fy - (float)y0;
    int x0 = (int)floorf(fx); float wx = fx - (float)x0;
    int y1 = min(y0 + 1, r - 1); y0 = max(y0, 0);
    int x1 = min(x0 + 1, r - 1); x0 = max(x0, 0);
    const float* p = rgb + (size_t)b * r * r;
    float v = (1.f - wy) * ((1.f - wx) * p[y0 * r + x0] + wx * p[y0 * r + x1])
            +        wy  * ((1.f - wx) * p[y1 * r + x0] + wx * p[y1 * r + x1]);
    int oidx = (b << 16) | (oy << 8) | ox;
    acc[oidx] = (beta ? acc[oidx] : 0.f) + v;
}

__global__ void k_final(const float* __restrict__ acc, float* __restrict__ out, int total) {
    int idx = blockIdx.x * blockDim.x + threadIdx.x;
    if (idx < total) out[idx] = acc[idx] * 0.5f + 0.5f;
}

extern "C" void kernel_launch(void* const* d_in, const int* in_sizes, int n_in,
                              void* d_out, int out_size, void* d_ws, size_t ws_size,
                              hipStream_t stream) {
    const float* w     = (const float*)d_in[0];
    const float* noise[4] = {(const float*)d_in[1], (const float*)d_in[2],
                             (const float*)d_in[3], (const float*)d_in[4]};
    const float* ic    = (const float*)d_in[5];
    const float* tsw   = (const float*)d_in[6];
    const float* tsb   = (const float*)d_in[7];
    const float* cw    = (const float*)d_in[8];
    const float* snp   = (const float*)d_in[9];
    const float* sbias = (const float*)d_in[10];
    const float* rgbw  = (const float*)d_in[11];

    // ws layout: s(16K) d(32K) acc(2M) rgb(2M) Wm(18.87M) bufA bufB
    const size_t WM_BYTES = 8ull * 8 * 9 * 128 * 128 * 2; // 18,874,368
    const size_t FIXED = 16384 + 32768 + 2097152 + 2097152 + WM_BYTES; // 23,117,824
    const size_t PER_S = 65536ull * 128 * 2; // 16,777,216 per sample per buffer
    int g = 0;
    for (int cand = 8; cand >= 1; cand >>= 1)
        if (ws_size >= FIXED + 2ull * cand * PER_S) { g = cand; break; }
    if (g == 0) return;

    char* ws = (char*)d_ws;
    float* s_all   = (float*)ws;
    float* d_all   = (float*)(ws + 16384);
    float* accb    = (float*)(ws + 49152);
    float* rgbb    = (float*)(ws + 2146304);
    ushortT* wmall = (ushortT*)(ws + 4243456);
    ushortT* bufA  = (ushortT*)(ws + FIXED);
    ushortT* bufB  = (ushortT*)(ws + FIXED + (size_t)g * PER_S);

    k_style<<<64, 64, 0, stream>>>(w, tsw, tsb, s_all);
    k_demod<<<1024, 64, 0, stream>>>(cw, s_all, d_all);
    k_wmod<<<36864, 256, 0, stream>>>(cw, s_all, wmall, 8 * 8 * 9 * 16384);

    for (int b0 = 0; b0 < BATCH; b0 += g) {
        ushortT* xb = bufA;
        ushortT* tb = bufB;
        int t0 = g * 1024 * 128;
        k_prep_init<<<(t0 + 255) / 256, 256, 0, stream>>>(ic, xb, t0);
        for (int i = 0; i < NB; ++i) {
            int r = 32 << i;
            if (i > 0) {
                int total = g * r * r * 16;
                int blocks = (total + 255) / 256;
                if (blocks > 2048) blocks = 2048;
                k_up2_bf<<<blocks, 256, 0, stream>>>(xb, tb, r / 2, r / 2, total);
                ushortT* tmp = xb; xb = tb; tb = tmp;
            }
            const float* s_i = s_all + i * BATCH * NF;
            for (int j = 0; j < 2; ++j) {
                int l = i * 2 + j;
                const ushortT* wl = wmall + (size_t)l * 8 * 9 * 16384;
                const float* dl = d_all + l * BATCH * NF;
                const float* nzp = noise[i] + (size_t)j * BATCH * r * r;
                const float* bs = sbias + l * NF;
                dim3 grid((r / 8) * (r / 8), g);
                k_conv_mfma<<<grid, 256, 0, stream>>>(xb, tb, wl, dl, nzp, bs,
                                                      snp + l, r, r, b0);
                ushortT* tmp = xb; xb = tb; tb = tmp;
            }
            int HW = r * r;
            int bx = (HW + 255) / 256;
            if (bx > 1024) bx = 1024;
            dim3 rgrid(bx, g);
            k_rgb_bf<<<rgrid, 256, 0, stream>>>(xb, rgbb, rgbw + i * NF, s_i, HW, b0);
            int tot = g * 256 * 256;
            k_rgbacc<<<(tot + 255) / 256, 256, 0, stream>>>(rgbb, accb, r, i, b0, g);
        }
    }
    k_final<<<(out_size + 255) / 256, 256, 0, stream>>>(accb, (float*)d_out, out_size);
}

// Round 4
// 1916.046 us; speedup vs baseline: 15.0542x; 1.0366x over previous
//
#include <hip/hip_runtime.h>
#include <math.h>

#define NB 4
#define BATCH 8
#define NF 128
#define WDIM 512
#define EPS_D 1e-8f

typedef unsigned short ushortT;
typedef __attribute__((ext_vector_type(8))) short short8v;
typedef __attribute__((ext_vector_type(8))) unsigned short ushort8v;
typedef __attribute__((ext_vector_type(4))) float float4v;
typedef __attribute__((ext_vector_type(4))) unsigned int uint4v;
typedef __attribute__((ext_vector_type(2))) unsigned int uint2v;

__device__ inline unsigned short f2bf(float f) {
    unsigned u = __builtin_bit_cast(unsigned, f);
    u = (u + 0x7fffu + ((u >> 16) & 1u)) >> 16;
    return (unsigned short)u;
}
__device__ inline float bf2f(unsigned short h) {
    unsigned u = ((unsigned)h) << 16;
    return __builtin_bit_cast(float, u);
}

// ---------------- style
__global__ void k_style(const float* __restrict__ w,
                        const float* __restrict__ tsw,
                        const float* __restrict__ tsb,
                        float* __restrict__ s) {
    int gid = blockIdx.x * blockDim.x + threadIdx.x;
    if (gid >= NB * BATCH * NF) return;
    int i = gid >> 10;
    int b = (gid >> 7) & 7;
    int o = gid & 127;
    const float cl = 0.044194173824159216f; // 1/sqrt(512)
    const float* wr = w + (i * BATCH + b) * WDIM;
    const float* tr = tsw + (i * NF + o) * WDIM;
    float acc = 0.f;
    for (int k = 0; k < WDIM; ++k) acc += wr[k] * tr[k];
    s[gid] = acc * cl + tsb[i * NF + o];
}

// ---------------- demod (f32 exact)
__global__ void k_demod(const float* __restrict__ conv_w,
                        const float* __restrict__ s,
                        float* __restrict__ d) {
    int bx = blockIdx.x; // l*128 + o
    int l = bx >> 7;
    int o = bx & 127;
    int lane = threadIdx.x;
    const float* wb = conv_w + (size_t)((l * NF + o) * NF) * 9;
    float t0 = 0.f, t1 = 0.f;
    for (int k = 0; k < 9; ++k) {
        float a = wb[lane * 9 + k];        t0 += a * a;
        float c = wb[(lane + 64) * 9 + k]; t1 += c * c;
    }
    const float c2 = 1.0f / 1152.0f;
    int i = l >> 1;
    for (int b = 0; b < BATCH; ++b) {
        float s0 = s[(i * BATCH + b) * NF + lane];
        float s1 = s[(i * BATCH + b) * NF + lane + 64];
        float v = t0 * s0 * s0 + t1 * s1 * s1;
        for (int off = 32; off > 0; off >>= 1) v += __shfl_down(v, off);
        if (lane == 0) d[(l * BATCH + b) * NF + o] = rsqrtf(v * c2 + EPS_D);
    }
}

// ---------------- fragment-major modulated weights
// wmF[l][b][tap][kcc(4)][mf(8)][lane(64)][e(8)] bf16
// lane: co = mf*16 + (lane&15), k = kcc*32 + (lane>>4)*8 + e
__global__ void k_wmodF(const float* __restrict__ cw, const float* __restrict__ s,
                        ushortT* __restrict__ wm) {
    int idx = blockIdx.x * blockDim.x + threadIdx.x; // 1,179,648
    int lane = idx & 63;
    int mf = (idx >> 6) & 7;
    int kcc = (idx >> 9) & 3;
    int t = (idx >> 11) % 9;
    int r2 = idx / (2048 * 9);
    int b = r2 & 7;
    int l = r2 >> 3;
    if (l >= 8) return;
    const float cscale = 0.029462782549439483f; // 1/sqrt(1152)
    int co = mf * 16 + (lane & 15);
    int kb = kcc * 32 + (lane >> 4) * 8;
    const float* src = cw + (((size_t)l * NF + co) * NF) * 9;
    const float* sr = s + ((l >> 1) * BATCH + b) * NF;
    ushort8v o;
    #pragma unroll
    for (int e = 0; e < 8; ++e) {
        int ci = kb + e;
        o[e] = f2bf(src[(size_t)ci * 9 + t] * cscale * sr[ci]);
    }
    *(ushort8v*)(wm + (size_t)idx * 8) = o;
}

// ---------------- initial constant -> relu -> bf16 NHWC (g samples)
__global__ void k_prep_init(const float* __restrict__ ic, ushortT* __restrict__ xp,
                            int total) {
    for (int idx = blockIdx.x * blockDim.x + threadIdx.x; idx < total;
         idx += gridDim.x * blockDim.x) {
        int ci = idx & 127;
        int p = (idx >> 7) & 1023;
        float v = ic[ci * 1024 + p];
        xp[idx] = f2bf(v > 0.f ? v : 0.f);
    }
}

// ---------------- fused conv: [optional up2-in] + modconv3x3 + demod + noise
//                  + bias + leaky + [optional ToRGB]
// 16x16 px tile, 128 co; 4 waves, wave = 128co x 64px.
__global__ __launch_bounds__(256, 2) void k_conv2(
    const ushortT* __restrict__ xp, ushortT* __restrict__ yp,
    const ushortT* __restrict__ wF,   // layer base: [8b][9][4][8][64][8]
    const float* __restrict__ d_b,    // [8][128]
    const float* __restrict__ nz,     // [8][H][W]
    const float* __restrict__ bias,   // [128]
    const float* __restrict__ sn_ptr,
    const float* __restrict__ s_blk,  // [8][128] (for rgb coeff)
    const float* __restrict__ rgbw_i, // [128]
    float* __restrict__ rgbb,         // [8][H][W] f32
    int H, int W, int b0, int up2, int do_rgb)
{
    __shared__ uint4v ldsq[4096];     // 64 KiB
    char* lb = (char*)ldsq;
    int tid = threadIdx.x;
    int lane = tid & 63;
    int wn = tid >> 6;
    int lm = lane & 15, lk = lane >> 4;
    int tilesX = W >> 4;
    int tx0 = (blockIdx.x % tilesX) << 4;
    int ty0 = (blockIdx.x / tilesX) << 4;
    int zb = blockIdx.y;
    int b = b0 + zb;

    float4v acc[8][4];
    #pragma unroll
    for (int mf = 0; mf < 8; ++mf)
        #pragma unroll
        for (int nf = 0; nf < 4; ++nf)
            acc[mf][nf] = (float4v){0.f, 0.f, 0.f, 0.f};

    const ushortT* wB = wF + (size_t)b * (9 * 4 * 4096);

    for (int cih = 0; cih < 2; ++cih) {
        if (cih) __syncthreads();
        if (!up2) {
            for (int c = tid; c < 2592; c += 256) {
                int hp = c >> 3, ck = c & 7;
                int hy = hp / 18, hx = hp - hy * 18;
                int gy = ty0 + hy - 1, gx = tx0 + hx - 1;
                uint4v v = {0, 0, 0, 0};
                if ((unsigned)gy < (unsigned)H && (unsigned)gx < (unsigned)W)
                    v = *(const uint4v*)(xp + (((size_t)zb * H + gy) * W + gx) * 128
                                         + cih * 64 + ck * 8);
                *(uint4v*)(lb + hp * 128 + ((ck << 4) ^ ((hp & 7) << 4))) = v;
            }
        } else {
            int h = H >> 1, w = W >> 1;
            for (int c = tid; c < 2592; c += 256) {
                int hp = c >> 3, ck = c & 7;
                int hy = hp / 18, hx = hp - hy * 18;
                int gy = ty0 + hy - 1, gx = tx0 + hx - 1;
                uint4v vv = {0, 0, 0, 0};
                if ((unsigned)gy < (unsigned)H && (unsigned)gx < (unsigned)W) {
                    int y0 = (gy >> 1) - 1 + (gy & 1);
                    float wy0 = (gy & 1) ? 0.75f : 0.25f;
                    int x0 = (gx >> 1) - 1 + (gx & 1);
                    float wx0 = (gx & 1) ? 0.75f : 0.25f;
                    int y1 = min(y0 + 1, h - 1); y0 = max(y0, 0);
                    int x1 = min(x0 + 1, w - 1); x0 = max(x0, 0);
                    const ushortT* base = xp + (size_t)zb * h * w * 128 + cih * 64 + ck * 8;
                    ushort8v v00 = *(const ushort8v*)(base + (size_t)(y0 * w + x0) * 128);
                    ushort8v v01 = *(const ushort8v*)(base + (size_t)(y0 * w + x1) * 128);
                    ushort8v v10 = *(const ushort8v*)(base + (size_t)(y1 * w + x0) * 128);
                    ushort8v v11 = *(const ushort8v*)(base + (size_t)(y1 * w + x1) * 128);
                    float wy1 = 1.f - wy0, wx1 = 1.f - wx0;
                    ushort8v o;
                    #pragma unroll
                    for (int e = 0; e < 8; ++e) {
                        float v = wy0 * (wx0 * bf2f(v00[e]) + wx1 * bf2f(v01[e]))
                                + wy1 * (wx0 * bf2f(v10[e]) + wx1 * bf2f(v11[e]));
                        o[e] = f2bf(v);
                    }
                    vv = __builtin_bit_cast(uint4v, o);
                }
                *(uint4v*)(lb + hp * 128 + ((ck << 4) ^ ((hp & 7) << 4))) = vv;
            }
        }
        __syncthreads();

        for (int tap = 0; tap < 9; ++tap) {
            int dy = (tap < 3) ? 0 : (tap < 6 ? 1 : 2);
            int dx = tap - dy * 3;
            #pragma unroll
            for (int kc = 0; kc < 2; ++kc) {
                int kcc = cih * 2 + kc;
                const ushortT* ap = wB + (size_t)(tap * 4 + kcc) * 4096 + lane * 8;
                short8v a[8];
                #pragma unroll
                for (int mf = 0; mf < 8; ++mf)
                    a[mf] = *(const short8v*)(ap + mf * 512);
                short8v bf[4];
                #pragma unroll
                for (int nf = 0; nf < 4; ++nf) {
                    int hp = (wn * 4 + nf + dy) * 18 + lm + dx;
                    int off = hp * 128 + (((kc * 32 + lk * 8) * 2) ^ ((hp & 7) << 4));
                    bf[nf] = *(const short8v*)(lb + off);
                }
                #pragma unroll
                for (int mf = 0; mf < 8; ++mf)
                    #pragma unroll
                    for (int nf = 0; nf < 4; ++nf)
                        acc[mf][nf] = __builtin_amdgcn_mfma_f32_16x16x32_bf16(
                            a[mf], bf[nf], acc[mf][nf], 0, 0, 0);
            }
        }
    }
    __syncthreads();   // all halo reads done; reuse LDS for output transpose

    float sn = sn_ptr[0];
    float nv[4];
    #pragma unroll
    for (int nf = 0; nf < 4; ++nf) {
        int gy = ty0 + wn * 4 + nf, gx = tx0 + lm;
        nv[nf] = sn * nz[((size_t)b * H + gy) * W + gx];
    }
    float rgbs[4] = {0.f, 0.f, 0.f, 0.f};
    const float cl2 = 0.08838834764831845f; // 1/sqrt(128)
    #pragma unroll
    for (int mf = 0; mf < 8; ++mf) {
        int co0 = mf * 16 + lk * 4;
        float4v dd = *(const float4v*)(d_b + b * 128 + co0);
        float4v bb = *(const float4v*)(bias + co0);
        float4v cf = {0.f, 0.f, 0.f, 0.f};
        if (do_rgb) {
            float4v rw = *(const float4v*)(rgbw_i + co0);
            float4v sv = *(const float4v*)(s_blk + b * 128 + co0);
            #pragma unroll
            for (int e = 0; e < 4; ++e) cf[e] = rw[e] * cl2 * sv[e];
        }
        #pragma unroll
        for (int nf = 0; nf < 4; ++nf) {
            float v[4];
            #pragma unroll
            for (int e = 0; e < 4; ++e) {
                float t = acc[mf][nf][e] * dd[e] + nv[nf] + bb[e];
                v[e] = t > 0.f ? t : 0.2f * t;
            }
            if (do_rgb)
                rgbs[nf] += v[0] * cf[0] + v[1] * cf[1] + v[2] * cf[2] + v[3] * cf[3];
            int px = wn * 64 + nf * 16 + lm;
            uint2v pk;
            pk[0] = (unsigned)f2bf(v[0]) | ((unsigned)f2bf(v[1]) << 16);
            pk[1] = (unsigned)f2bf(v[2]) | ((unsigned)f2bf(v[3]) << 16);
            *(uint2v*)(lb + px * 256 + ((co0 * 2) ^ (lm << 4))) = pk;
        }
    }
    if (do_rgb) {
        #pragma unroll
        for (int nf = 0; nf < 4; ++nf) {
            float r = rgbs[nf];
            r += __shfl_xor(r, 16, 64);
            r += __shfl_xor(r, 32, 64);
            if (lane < 16) {
                int gy = ty0 + wn * 4 + nf, gx = tx0 + lane;
                rgbb[(size_t)b * H * W + (size_t)gy * W + gx] = r;
            }
        }
    }
    __syncthreads();
    for (int c = tid; c < 4096; c += 256) {
        int px = c >> 4, ck = c & 15;
        uint4v v = *(const uint4v*)(lb + px * 256 + ((ck << 4) ^ ((px & 15) << 4)));
        int gy = ty0 + (px >> 4), gx = tx0 + (px & 15);
        *(uint4v*)(yp + (((size_t)zb * H + gy) * W + gx) * 128 + ck * 8) = v;
    }
}

// ---------------- bilinear upsample rgb (r->256) and accumulate
__global__ void k_rgbacc(const float* __restrict__ rgb, float* __restrict__ acc,
                         int r, int beta, int b0, int g) {
    int idx = blockIdx.x * blockDim.x + threadIdx.x;
    if (idx >= g * 256 * 256) return;
    int ox = idx & 255;
    int oy = (idx >> 8) & 255;
    int b = b0 + (idx >> 16);
    float scale = (float)r * (1.0f / 256.0f);
    float fy = (oy + 0.5f) * scale - 0.5f;
    float fx = (ox + 0.5f) * scale - 0.5f;
    int y0 = (int)floorf(fy); float wy = fy - (float)y0;
    int x0 = (int)floorf(fx); float wx = fx - (float)x0;
    int y1 = min(y0 + 1, r - 1); y0 = max(y0, 0);
    int x1 = min(x0 + 1, r - 1); x0 = max(x0, 0);
    const float* p = rgb + (size_t)b * r * r;
    float v = (1.f - wy) * ((1.f - wx) * p[y0 * r + x0] + wx * p[y0 * r + x1])
            +        wy  * ((1.f - wx) * p[y1 * r + x0] + wx * p[y1 * r + x1]);
    int oidx = (b << 16) | (oy << 8) | ox;
    acc[oidx] = (beta ? acc[oidx] : 0.f) + v;
}

__global__ void k_final(const float* __restrict__ acc, float* __restrict__ out, int total) {
    int idx = blockIdx.x * blockDim.x + threadIdx.x;
    if (idx < total) out[idx] = acc[idx] * 0.5f + 0.5f;
}

extern "C" void kernel_launch(void* const* d_in, const int* in_sizes, int n_in,
                              void* d_out, int out_size, void* d_ws, size_t ws_size,
                              hipStream_t stream) {
    const float* w     = (const float*)d_in[0];
    const float* noise[4] = {(const float*)d_in[1], (const float*)d_in[2],
                             (const float*)d_in[3], (const float*)d_in[4]};
    const float* ic    = (const float*)d_in[5];
    const float* tsw   = (const float*)d_in[6];
    const float* tsb   = (const float*)d_in[7];
    const float* cw    = (const float*)d_in[8];
    const float* snp   = (const float*)d_in[9];
    const float* sbias = (const float*)d_in[10];
    const float* rgbw  = (const float*)d_in[11];

    const size_t WM_BYTES = 8ull * 8 * 9 * 4 * 8 * 64 * 8 * 2; // 18,874,368
    const size_t FIXED = 16384 + 32768 + 2097152 + 2097152 + WM_BYTES;
    const size_t PER_S = 65536ull * 128 * 2; // 16,777,216 per sample per buffer
    int g = 0;
    for (int cand = 8; cand >= 1; cand >>= 1)
        if (ws_size >= FIXED + 2ull * cand * PER_S) { g = cand; break; }
    if (g == 0) return;

    char* ws = (char*)d_ws;
    float* s_all   = (float*)ws;
    float* d_all   = (float*)(ws + 16384);
    float* accb    = (float*)(ws + 49152);
    float* rgbb    = (float*)(ws + 2146304);
    ushortT* wmall = (ushortT*)(ws + 4243456);
    ushortT* bufA  = (ushortT*)(ws + FIXED);
    ushortT* bufB  = (ushortT*)(ws + FIXED + (size_t)g * PER_S);

    k_style<<<64, 64, 0, stream>>>(w, tsw, tsb, s_all);
    k_demod<<<1024, 64, 0, stream>>>(cw, s_all, d_all);
    k_wmodF<<<4608, 256, 0, stream>>>(cw, s_all, wmall);

    for (int b0 = 0; b0 < BATCH; b0 += g) {
        ushortT* xb = bufA;
        ushortT* tb = bufB;
        int t0 = g * 1024 * 128;
        k_prep_init<<<(t0 + 255) / 256, 256, 0, stream>>>(ic, xb, t0);
        for (int i = 0; i < NB; ++i) {
            int r = 32 << i;
            const float* s_i = s_all + i * BATCH * NF;
            for (int j = 0; j < 2; ++j) {
                int l = i * 2 + j;
                const ushortT* wl = wmall + (size_t)l * (8 * 9 * 4 * 4096);
                const float* dl = d_all + l * BATCH * NF;
                const float* nzp = noise[i] + (size_t)j * BATCH * r * r;
                const float* bs = sbias + l * NF;
                int up2 = (i > 0 && j == 0) ? 1 : 0;
                int dorgb = (j == 1) ? 1 : 0;
                dim3 grid((r / 16) * (r / 16), g);
                k_conv2<<<grid, 256, 0, stream>>>(xb, tb, wl, dl, nzp, bs,
                                                  snp + l, s_i, rgbw + i * NF, rgbb,
                                                  r, r, b0, up2, dorgb);
                ushortT* tmp = xb; xb = tb; tb = tmp;
            }
            int tot = g * 256 * 256;
            k_rgbacc<<<(tot + 255) / 256, 256, 0, stream>>>(rgbb, accb, r, i, b0, g);
        }
    }
    k_final<<<(out_size + 255) / 256, 256, 0, stream>>>(accb, (float*)d_out, out_size);
}

// Round 6
// 1480.949 us; speedup vs baseline: 19.4771x; 1.2938x over previous
//
#include <hip/hip_runtime.h>
#include <math.h>

#define NB 4
#define BATCH 8
#define NF 128
#define WDIM 512
#define EPS_D 1e-8f

typedef unsigned short ushortT;
typedef __attribute__((ext_vector_type(8))) short short8v;
typedef __attribute__((ext_vector_type(8))) unsigned short ushort8v;
typedef __attribute__((ext_vector_type(4))) float float4v;
typedef __attribute__((ext_vector_type(4))) unsigned int uint4v;
typedef __attribute__((ext_vector_type(2))) unsigned int uint2v;

__device__ inline unsigned short f2bf(float f) {
    unsigned u = __builtin_bit_cast(unsigned, f);
    u = (u + 0x7fffu + ((u >> 16) & 1u)) >> 16;
    return (unsigned short)u;
}
__device__ inline float bf2f(unsigned short h) {
    unsigned u = ((unsigned)h) << 16;
    return __builtin_bit_cast(float, u);
}

// ---------------- style
__global__ void k_style(const float* __restrict__ w,
                        const float* __restrict__ tsw,
                        const float* __restrict__ tsb,
                        float* __restrict__ s) {
    int gid = blockIdx.x * blockDim.x + threadIdx.x;
    if (gid >= NB * BATCH * NF) return;
    int i = gid >> 10;
    int b = (gid >> 7) & 7;
    int o = gid & 127;
    const float cl = 0.044194173824159216f; // 1/sqrt(512)
    const float* wr = w + (i * BATCH + b) * WDIM;
    const float* tr = tsw + (i * NF + o) * WDIM;
    float acc = 0.f;
    for (int k = 0; k < WDIM; ++k) acc += wr[k] * tr[k];
    s[gid] = acc * cl + tsb[i * NF + o];
}

// ---------------- demod (f32 exact)
__global__ void k_demod(const float* __restrict__ conv_w,
                        const float* __restrict__ s,
                        float* __restrict__ d) {
    int bx = blockIdx.x; // l*128 + o
    int l = bx >> 7;
    int o = bx & 127;
    int lane = threadIdx.x;
    const float* wb = conv_w + (size_t)((l * NF + o) * NF) * 9;
    float t0 = 0.f, t1 = 0.f;
    for (int k = 0; k < 9; ++k) {
        float a = wb[lane * 9 + k];        t0 += a * a;
        float c = wb[(lane + 64) * 9 + k]; t1 += c * c;
    }
    const float c2 = 1.0f / 1152.0f;
    int i = l >> 1;
    for (int b = 0; b < BATCH; ++b) {
        float s0 = s[(i * BATCH + b) * NF + lane];
        float s1 = s[(i * BATCH + b) * NF + lane + 64];
        float v = t0 * s0 * s0 + t1 * s1 * s1;
        for (int off = 32; off > 0; off >>= 1) v += __shfl_down(v, off);
        if (lane == 0) d[(l * BATCH + b) * NF + o] = rsqrtf(v * c2 + EPS_D);
    }
}

// ---------------- fragment-major modulated weights
// wmF[l][b][tap][kcc(4)][mf(8)][lane(64)][e(8)] bf16; lane = lk*16+lm
__global__ void k_wmodF(const float* __restrict__ cw, const float* __restrict__ s,
                        ushortT* __restrict__ wm) {
    int idx = blockIdx.x * blockDim.x + threadIdx.x; // 1,179,648
    int lane = idx & 63;
    int mf = (idx >> 6) & 7;
    int kcc = (idx >> 9) & 3;
    int t = (idx >> 11) % 9;
    int r2 = idx / (2048 * 9);
    int b = r2 & 7;
    int l = r2 >> 3;
    if (l >= 8) return;
    const float cscale = 0.029462782549439483f; // 1/sqrt(1152)
    int co = mf * 16 + (lane & 15);
    int kb = kcc * 32 + (lane >> 4) * 8;
    const float* src = cw + (((size_t)l * NF + co) * NF) * 9;
    const float* sr = s + ((l >> 1) * BATCH + b) * NF;
    ushort8v o;
    #pragma unroll
    for (int e = 0; e < 8; ++e) {
        int ci = kb + e;
        o[e] = f2bf(src[(size_t)ci * 9 + t] * cscale * sr[ci]);
    }
    *(ushort8v*)(wm + (size_t)idx * 8) = o;
}

// ---------------- initial constant -> relu -> bf16 NHWC (g samples)
__global__ void k_prep_init(const float* __restrict__ ic, ushortT* __restrict__ xp,
                            int total) {
    for (int idx = blockIdx.x * blockDim.x + threadIdx.x; idx < total;
         idx += gridDim.x * blockDim.x) {
        int ci = idx & 127;
        int p = (idx >> 7) & 1023;
        float v = ic[ci * 1024 + p];
        xp[idx] = f2bf(v > 0.f ? v : 0.f);
    }
}

// ============ fused conv: [up2-in] + modconv3x3 + demod + noise + bias
//              + leaky + [ToRGB partial]
// 16x16 px tile, 512 thr (8 waves); wave = 64co (wm) x 64px (wn quarter).
// ci processed in 4 quarters of 32, double-buffered LDS, 1 barrier/quarter.
template<int UP2>
__global__ __launch_bounds__(512, 4) void k_conv3(
    const ushortT* __restrict__ xp, ushortT* __restrict__ yp,
    const ushortT* __restrict__ wF,   // [8b][9][4][8][64][8]
    const float* __restrict__ d_b,    // [8][128]
    const float* __restrict__ nz,     // [8][H][W]
    const float* __restrict__ bias,   // [128]
    const float* __restrict__ sn_ptr,
    const float* __restrict__ s_blk,  // [8][128]
    const float* __restrict__ rgbw_i, // [128]
    float* __restrict__ rgbb,         // [2][8][H][W] f32 partials
    int H, int W, int b0, int do_rgb)
{
    __shared__ __align__(16) char lb[41472];   // 2 x 20736 stage | 32768 transpose
    int tid = threadIdx.x;
    int lane = tid & 63;
    int wv = tid >> 6;
    int wm = wv & 1;       // co half
    int wn = wv >> 1;      // px quarter (16 rows /4)
    int lm = lane & 15, lk = lane >> 4;
    int tilesX = W >> 4;
    int tx0 = (blockIdx.x % tilesX) << 4;
    int ty0 = (blockIdx.x / tilesX) << 4;
    int zb = blockIdx.y;
    int b = b0 + zb;

    float4v acc[4][4];
    #pragma unroll
    for (int mf = 0; mf < 4; ++mf)
        #pragma unroll
        for (int nf = 0; nf < 4; ++nf)
            acc[mf][nf] = (float4v){0.f, 0.f, 0.f, 0.f};

    const ushortT* wB = wF + (size_t)b * (9 * 4 * 4096);

    // ---- per-thread staging descriptors (3 chunks of 16B per quarter) ----
    // chunk c: px = c>>2 (0..323), lds slot = c&3, global ci-slot = (c&3)^(px&3)
    int goff0 = -1, goff1 = -1, goff2 = -1;   // plain: global byte offset
    int loff0 = -1, loff1 = -1, loff2 = -1;   // lds byte offset
    // up2 descriptors
    int u00[3], u01[3], u10[3], u11[3];
    float uwy[3], uwx[3];
    const char* xbase;
    if (!UP2) {
        xbase = (const char*)(xp + (size_t)zb * H * W * 128);
        #pragma unroll
        for (int k = 0; k < 3; ++k) {
            int c = tid + k * 512;
            if (c < 1296) {
                int px = c >> 2;
                int hy = px / 18, hx = px - hy * 18;
                int gy = ty0 + hy - 1, gx = tx0 + hx - 1;
                int s = (c & 3) ^ (px & 3);
                int lo = px * 64 + (c & 3) * 16;
                int go = ((unsigned)gy < (unsigned)H && (unsigned)gx < (unsigned)W)
                         ? ((gy * W + gx) * 256 + s * 16) : -1;
                if (k == 0) { goff0 = go; loff0 = lo; }
                else if (k == 1) { goff1 = go; loff1 = lo; }
                else { goff2 = go; loff2 = lo; }
            }
        }
    } else {
        int h2 = H >> 1, w2 = W >> 1;
        xbase = (const char*)(xp + (size_t)zb * h2 * w2 * 128);
        #pragma unroll
        for (int k = 0; k < 3; ++k) {
            u00[k] = -1;
            int c = tid + k * 512;
            if (c < 1296) {
                int px = c >> 2;
                int hy = px / 18, hx = px - hy * 18;
                int gy = ty0 + hy - 1, gx = tx0 + hx - 1;
                int s = (c & 3) ^ (px & 3);
                int lo = px * 64 + (c & 3) * 16;
                if (k == 0) loff0 = lo; else if (k == 1) loff1 = lo; else loff2 = lo;
                if ((unsigned)gy < (unsigned)H && (unsigned)gx < (unsigned)W) {
                    int y0 = (gy >> 1) - 1 + (gy & 1);
                    uwy[k] = (gy & 1) ? 0.75f : 0.25f;
                    int x0 = (gx >> 1) - 1 + (gx & 1);
                    uwx[k] = (gx & 1) ? 0.75f : 0.25f;
                    int y1 = min(y0 + 1, h2 - 1); y0 = max(y0, 0);
                    int x1 = min(x0 + 1, w2 - 1); x0 = max(x0, 0);
                    u00[k] = (y0 * w2 + x0) * 256 + s * 16;
                    u01[k] = (y0 * w2 + x1) * 256 + s * 16;
                    u10[k] = (y1 * w2 + x0) * 256 + s * 16;
                    u11[k] = (y1 * w2 + x1) * 256 + s * 16;
                }
            }
        }
    }

    uint4v pf0 = {0,0,0,0}, pf1 = {0,0,0,0}, pf2 = {0,0,0,0};
    const uint4v zv = {0, 0, 0, 0};

    #define PFETCH(q) do { \
        if (!UP2) { \
            pf0 = (goff0 >= 0) ? *(const uint4v*)(xbase + goff0 + (q) * 64) : zv; \
            pf1 = (goff1 >= 0) ? *(const uint4v*)(xbase + goff1 + (q) * 64) : zv; \
            pf2 = (goff2 >= 0) ? *(const uint4v*)(xbase + goff2 + (q) * 64) : zv; \
        } else { \
            uint4v* pfp[3] = {&pf0, &pf1, &pf2}; \
            _Pragma("unroll") \
            for (int k = 0; k < 3; ++k) { \
                uint4v r = zv; \
                if (u00[k] >= 0) { \
                    ushort8v v00 = *(const ushort8v*)(xbase + u00[k] + (q) * 64); \
                    ushort8v v01 = *(const ushort8v*)(xbase + u01[k] + (q) * 64); \
                    ushort8v v10 = *(const ushort8v*)(xbase + u10[k] + (q) * 64); \
                    ushort8v v11 = *(const ushort8v*)(xbase + u11[k] + (q) * 64); \
                    float wy0 = uwy[k], wx0 = uwx[k]; \
                    float wy1 = 1.f - wy0, wx1 = 1.f - wx0; \
                    ushort8v o; \
                    _Pragma("unroll") \
                    for (int e = 0; e < 8; ++e) { \
                        float v = wy0 * (wx0 * bf2f(v00[e]) + wx1 * bf2f(v01[e])) \
                                + wy1 * (wx0 * bf2f(v10[e]) + wx1 * bf2f(v11[e])); \
                        o[e] = f2bf(v); \
                    } \
                    r = __builtin_bit_cast(uint4v, o); \
                } \
                *pfp[k] = r; \
            } \
        } \
    } while (0)

    PFETCH(0);

    for (int q = 0; q < 4; ++q) {
        char* buf = lb + (q & 1) * 20736;
        if (loff0 >= 0) *(uint4v*)(buf + loff0) = pf0;
        if (loff1 >= 0) *(uint4v*)(buf + loff1) = pf1;
        if (loff2 >= 0) *(uint4v*)(buf + loff2) = pf2;
        if (q < 3) {
            if (q == 0) PFETCH(1);
            else if (q == 1) PFETCH(2);
            else PFETCH(3);
        }
        __syncthreads();
        #pragma unroll
        for (int tap = 0; tap < 9; ++tap) {
            const int dy = (tap < 3) ? 0 : (tap < 6 ? 1 : 2);
            const int dx = tap - dy * 3;
            const ushortT* ap = wB + ((tap * 4 + q) << 12) + wm * 2048 + lane * 8;
            short8v a0 = *(const short8v*)(ap);
            short8v a1 = *(const short8v*)(ap + 512);
            short8v a2 = *(const short8v*)(ap + 1024);
            short8v a3 = *(const short8v*)(ap + 1536);
            #pragma unroll
            for (int nf = 0; nf < 4; ++nf) {
                int hp = (wn * 4 + nf + dy) * 18 + lm + dx;
                short8v bf = *(const short8v*)(buf + hp * 64 + ((lk << 4) ^ ((hp & 3) << 4)));
                acc[0][nf] = __builtin_amdgcn_mfma_f32_16x16x32_bf16(a0, bf, acc[0][nf], 0, 0, 0);
                acc[1][nf] = __builtin_amdgcn_mfma_f32_16x16x32_bf16(a1, bf, acc[1][nf], 0, 0, 0);
                acc[2][nf] = __builtin_amdgcn_mfma_f32_16x16x32_bf16(a2, bf, acc[2][nf], 0, 0, 0);
                acc[3][nf] = __builtin_amdgcn_mfma_f32_16x16x32_bf16(a3, bf, acc[3][nf], 0, 0, 0);
            }
        }
        __syncthreads();
    }

    // ---------------- epilogue ----------------
    float sn = sn_ptr[0];
    float nv[4];
    #pragma unroll
    for (int nf = 0; nf < 4; ++nf) {
        int gy = ty0 + wn * 4 + nf, gx = tx0 + lm;
        nv[nf] = sn * nz[((size_t)b * H + gy) * W + gx];
    }
    const float cl2 = 0.08838834764831845f; // 1/sqrt(128)
    float rgbs[4] = {0.f, 0.f, 0.f, 0.f};
    unsigned pka[4][4][2]; // [mf][nf][2] packed bf16 pairs (co0..co0+3)
    #pragma unroll
    for (int mf = 0; mf < 4; ++mf) {
        int co0 = wm * 64 + mf * 16 + lk * 4;
        float4v dd = *(const float4v*)(d_b + b * 128 + co0);
        float4v bb = *(const float4v*)(bias + co0);
        float4v cf = {0.f, 0.f, 0.f, 0.f};
        if (do_rgb) {
            float4v rw = *(const float4v*)(rgbw_i + co0);
            float4v sv = *(const float4v*)(s_blk + b * 128 + co0);
            #pragma unroll
            for (int e = 0; e < 4; ++e) cf[e] = rw[e] * cl2 * sv[e];
        }
        #pragma unroll
        for (int nf = 0; nf < 4; ++nf) {
            float v[4];
            #pragma unroll
            for (int e = 0; e < 4; ++e) {
                float t = acc[mf][nf][e] * dd[e] + nv[nf] + bb[e];
                v[e] = t > 0.f ? t : 0.2f * t;
            }
            if (do_rgb)
                rgbs[nf] += v[0] * cf[0] + v[1] * cf[1] + v[2] * cf[2] + v[3] * cf[3];
            pka[mf][nf][0] = (unsigned)f2bf(v[0]) | ((unsigned)f2bf(v[1]) << 16);
            pka[mf][nf][1] = (unsigned)f2bf(v[2]) | ((unsigned)f2bf(v[3]) << 16);
        }
    }
    if (do_rgb) {
        #pragma unroll
        for (int nf = 0; nf < 4; ++nf) {
            float r = rgbs[nf];
            r += __shfl_xor(r, 16, 64);
            r += __shfl_xor(r, 32, 64);
            if (lane < 16) {
                int gy = ty0 + wn * 4 + nf, gx = tx0 + lane;
                rgbb[((size_t)(wm * BATCH + b) * H + gy) * W + gx] = r;
            }
        }
    }
    // two co-half transpose rounds (32 KB each); co0..co0+3 stored as ONE
    // contiguous 8-byte uint2v (this was R5's bug: split +0/+8 stores
    // scrambled channel order and collided across lk).
    char* xb2 = (char*)(yp + (size_t)zb * H * W * 128);
    #pragma unroll
    for (int h = 0; h < 2; ++h) {
        if (wm == h) {
            #pragma unroll
            for (int mf = 0; mf < 4; ++mf) {
                int cb = (mf * 16 + lk * 4) * 2; // local co byte 0..120, 8-aligned
                #pragma unroll
                for (int nf = 0; nf < 4; ++nf) {
                    int px = (wn * 4 + nf) * 16 + lm;
                    int ad = px * 128 + (cb ^ ((px & 7) << 4));
                    uint2v pk2;
                    pk2[0] = pka[mf][nf][0];
                    pk2[1] = pka[mf][nf][1];
                    *(uint2v*)(lb + ad) = pk2;
                }
            }
        }
        __syncthreads();
        for (int c = tid; c < 2048; c += 512) {
            int px = c >> 3, ck = c & 7;
            uint4v v = *(const uint4v*)(lb + px * 128 + ((ck << 4) ^ ((px & 7) << 4)));
            int gy = ty0 + (px >> 4), gx = tx0 + (px & 15);
            *(uint4v*)(xb2 + ((size_t)(gy * W + gx)) * 256 + h * 128 + ck * 16) = v;
        }
        if (h == 0) __syncthreads();
    }
    #undef PFETCH
}

// ---------------- bilinear upsample rgb (r->256), sum 2 partial planes
__global__ void k_rgbacc(const float* __restrict__ rgb, float* __restrict__ acc,
                         int r, int beta, int b0, int g) {
    int idx = blockIdx.x * blockDim.x + threadIdx.x;
    if (idx >= g * 256 * 256) return;
    int ox = idx & 255;
    int oy = (idx >> 8) & 255;
    int b = b0 + (idx >> 16);
    float scale = (float)r * (1.0f / 256.0f);
    float fy = (oy + 0.5f) * scale - 0.5f;
    float fx = (ox + 0.5f) * scale - 0.5f;
    int y0 = (int)floorf(fy); float wy = fy - (float)y0;
    int x0 = (int)floorf(fx); float wx = fx - (float)x0;
    int y1 = min(y0 + 1, r - 1); y0 = max(y0, 0);
    int x1 = min(x0 + 1, r - 1); x0 = max(x0, 0);
    const float* p0 = rgb + (size_t)b * r * r;
    const float* p1 = rgb + (size_t)(BATCH + b) * r * r;
    float v00 = p0[y0 * r + x0] + p1[y0 * r + x0];
    float v01 = p0[y0 * r + x1] + p1[y0 * r + x1];
    float v10 = p0[y1 * r + x0] + p1[y1 * r + x0];
    float v11 = p0[y1 * r + x1] + p1[y1 * r + x1];
    float v = (1.f - wy) * ((1.f - wx) * v00 + wx * v01)
            +        wy  * ((1.f - wx) * v10 + wx * v11);
    int oidx = (b << 16) | (oy << 8) | ox;
    acc[oidx] = (beta ? acc[oidx] : 0.f) + v;
}

__global__ void k_final(float* __restrict__ out, int total) {
    int idx = blockIdx.x * blockDim.x + threadIdx.x;
    if (idx < total) out[idx] = out[idx] * 0.5f + 0.5f;
}

extern "C" void kernel_launch(void* const* d_in, const int* in_sizes, int n_in,
                              void* d_out, int out_size, void* d_ws, size_t ws_size,
                              hipStream_t stream) {
    const float* w     = (const float*)d_in[0];
    const float* noise[4] = {(const float*)d_in[1], (const float*)d_in[2],
                             (const float*)d_in[3], (const float*)d_in[4]};
    const float* ic    = (const float*)d_in[5];
    const float* tsw   = (const float*)d_in[6];
    const float* tsb   = (const float*)d_in[7];
    const float* cw    = (const float*)d_in[8];
    const float* snp   = (const float*)d_in[9];
    const float* sbias = (const float*)d_in[10];
    const float* rgbw  = (const float*)d_in[11];

    // ws: s(16K) d(32K) rgbb(4M, 2 planes) Wm(18.87M) bufA bufB ; acc = d_out
    const size_t WM_BYTES = 8ull * 8 * 9 * 4 * 8 * 64 * 8 * 2; // 18,874,368
    const size_t RGBB = 2ull * BATCH * 65536 * 4;              // 4,194,304
    const size_t FIXED = 16384 + 32768 + RGBB + WM_BYTES;      // 23,117,824
    const size_t PER_S = 65536ull * 128 * 2;                   // 16,777,216
    int g = 0;
    for (int cand = 8; cand >= 1; cand >>= 1)
        if (ws_size >= FIXED + 2ull * cand * PER_S) { g = cand; break; }
    if (g == 0) return;

    char* ws = (char*)d_ws;
    float* s_all   = (float*)ws;
    float* d_all   = (float*)(ws + 16384);
    float* rgbb    = (float*)(ws + 49152);
    ushortT* wmall = (ushortT*)(ws + 49152 + RGBB);
    ushortT* bufA  = (ushortT*)(ws + FIXED);
    ushortT* bufB  = (ushortT*)(ws + FIXED + (size_t)g * PER_S);
    float* accb    = (float*)d_out;

    k_style<<<64, 64, 0, stream>>>(w, tsw, tsb, s_all);
    k_demod<<<1024, 64, 0, stream>>>(cw, s_all, d_all);
    k_wmodF<<<4608, 256, 0, stream>>>(cw, s_all, wmall);

    for (int b0 = 0; b0 < BATCH; b0 += g) {
        ushortT* xb = bufA;
        ushortT* tb = bufB;
        int t0 = g * 1024 * 128;
        k_prep_init<<<(t0 + 255) / 256, 256, 0, stream>>>(ic, xb, t0);
        for (int i = 0; i < NB; ++i) {
            int r = 32 << i;
            const float* s_i = s_all + i * BATCH * NF;
            for (int j = 0; j < 2; ++j) {
                int l = i * 2 + j;
                const ushortT* wl = wmall + (size_t)l * (8 * 9 * 4 * 4096);
                const float* dl = d_all + l * BATCH * NF;
                const float* nzp = noise[i] + (size_t)j * BATCH * r * r;
                const float* bs = sbias + l * NF;
                int dorgb = (j == 1) ? 1 : 0;
                dim3 grid((r / 16) * (r / 16), g);
                if (i > 0 && j == 0)
                    k_conv3<1><<<grid, 512, 0, stream>>>(xb, tb, wl, dl, nzp, bs,
                        snp + l, s_i, rgbw + i * NF, rgbb, r, r, b0, dorgb);
                else
                    k_conv3<0><<<grid, 512, 0, stream>>>(xb, tb, wl, dl, nzp, bs,
                        snp + l, s_i, rgbw + i * NF, rgbb, r, r, b0, dorgb);
                ushortT* tmp = xb; xb = tb; tb = tmp;
            }
            int tot = g * 256 * 256;
            k_rgbacc<<<(tot + 255) / 256, 256, 0, stream>>>(rgbb, accb, r, i, b0, g);
        }
    }
    k_final<<<(out_size + 255) / 256, 256, 0, stream>>>(accb, out_size);
}

// Round 7
// 1180.235 us; speedup vs baseline: 24.4397x; 1.2548x over previous
//
#include <hip/hip_runtime.h>
#include <math.h>

#define NB 4
#define BATCH 8
#define NF 128
#define WDIM 512
#define EPS_D 1e-8f

typedef unsigned short ushortT;
typedef __attribute__((ext_vector_type(8))) short short8v;
typedef __attribute__((ext_vector_type(8))) unsigned short ushort8v;
typedef __attribute__((ext_vector_type(4))) float float4v;
typedef __attribute__((ext_vector_type(4))) unsigned int uint4v;
typedef __attribute__((ext_vector_type(2))) unsigned int uint2v;

__device__ inline unsigned short f2bf(float f) {
    unsigned u = __builtin_bit_cast(unsigned, f);
    u = (u + 0x7fffu + ((u >> 16) & 1u)) >> 16;
    return (unsigned short)u;
}
__device__ inline float bf2f(unsigned short h) {
    unsigned u = ((unsigned)h) << 16;
    return __builtin_bit_cast(float, u);
}

// ---------------- style
__global__ void k_style(const float* __restrict__ w,
                        const float* __restrict__ tsw,
                        const float* __restrict__ tsb,
                        float* __restrict__ s) {
    int gid = blockIdx.x * blockDim.x + threadIdx.x;
    if (gid >= NB * BATCH * NF) return;
    int i = gid >> 10;
    int b = (gid >> 7) & 7;
    int o = gid & 127;
    const float cl = 0.044194173824159216f; // 1/sqrt(512)
    const float* wr = w + (i * BATCH + b) * WDIM;
    const float* tr = tsw + (i * NF + o) * WDIM;
    float acc = 0.f;
    for (int k = 0; k < WDIM; ++k) acc += wr[k] * tr[k];
    s[gid] = acc * cl + tsb[i * NF + o];
}

// ---------------- demod (f32 exact)
__global__ void k_demod(const float* __restrict__ conv_w,
                        const float* __restrict__ s,
                        float* __restrict__ d) {
    int bx = blockIdx.x; // l*128 + o
    int l = bx >> 7;
    int o = bx & 127;
    int lane = threadIdx.x;
    const float* wb = conv_w + (size_t)((l * NF + o) * NF) * 9;
    float t0 = 0.f, t1 = 0.f;
    for (int k = 0; k < 9; ++k) {
        float a = wb[lane * 9 + k];        t0 += a * a;
        float c = wb[(lane + 64) * 9 + k]; t1 += c * c;
    }
    const float c2 = 1.0f / 1152.0f;
    int i = l >> 1;
    for (int b = 0; b < BATCH; ++b) {
        float s0 = s[(i * BATCH + b) * NF + lane];
        float s1 = s[(i * BATCH + b) * NF + lane + 64];
        float v = t0 * s0 * s0 + t1 * s1 * s1;
        for (int off = 32; off > 0; off >>= 1) v += __shfl_down(v, off);
        if (lane == 0) d[(l * BATCH + b) * NF + o] = rsqrtf(v * c2 + EPS_D);
    }
}

// ---------------- fragment-major modulated weights
// wmF[l][b][tap][kcc(4)][mf(8)][lane(64)][e(8)] bf16; lane = lk*16+lm
__global__ void k_wmodF(const float* __restrict__ cw, const float* __restrict__ s,
                        ushortT* __restrict__ wm) {
    int idx = blockIdx.x * blockDim.x + threadIdx.x; // 1,179,648
    int lane = idx & 63;
    int mf = (idx >> 6) & 7;
    int kcc = (idx >> 9) & 3;
    int t = (idx >> 11) % 9;
    int r2 = idx / (2048 * 9);
    int b = r2 & 7;
    int l = r2 >> 3;
    if (l >= 8) return;
    const float cscale = 0.029462782549439483f; // 1/sqrt(1152)
    int co = mf * 16 + (lane & 15);
    int kb = kcc * 32 + (lane >> 4) * 8;
    const float* src = cw + (((size_t)l * NF + co) * NF) * 9;
    const float* sr = s + ((l >> 1) * BATCH + b) * NF;
    ushort8v o;
    #pragma unroll
    for (int e = 0; e < 8; ++e) {
        int ci = kb + e;
        o[e] = f2bf(src[(size_t)ci * 9 + t] * cscale * sr[ci]);
    }
    *(ushort8v*)(wm + (size_t)idx * 8) = o;
}

// ---------------- initial constant -> relu -> bf16 NHWC (g samples)
__global__ void k_prep_init(const float* __restrict__ ic, ushortT* __restrict__ xp,
                            int total) {
    for (int idx = blockIdx.x * blockDim.x + threadIdx.x; idx < total;
         idx += gridDim.x * blockDim.x) {
        int ci = idx & 127;
        int p = (idx >> 7) & 1023;
        float v = ic[ci * 1024 + p];
        xp[idx] = f2bf(v > 0.f ? v : 0.f);
    }
}

// ============ fused conv: [up2-in] + modconv3x3 + demod + noise + bias
//              + leaky + [ToRGB partial]
// 16(w)x8(h) px tile, 256 thr (4 waves); wave = 64co (wm) x 64px (wn x-half).
// ci in 4 quarters of 32, double-buffered LDS, prefetch, 1 barrier/quarter.
// 22.5KB LDS + <=168 unified regs -> 3 blocks/CU (12 waves), no spill.
template<int UP2>
__global__ __launch_bounds__(256, 3) void k_conv4(
    const ushortT* __restrict__ xp, ushortT* __restrict__ yp,
    const ushortT* __restrict__ wF,   // [8b][9][4][8][64][8]
    const float* __restrict__ d_b,    // [8][128]
    const float* __restrict__ nz,     // [8][H][W]
    const float* __restrict__ bias,   // [128]
    const float* __restrict__ sn_ptr,
    const float* __restrict__ s_blk,  // [8][128]
    const float* __restrict__ rgbw_i, // [128]
    float* __restrict__ rgbb,         // [2][8][H][W] f32 partials
    int H, int W, int b0, int g, int do_rgb)
{
    __shared__ __align__(16) char lb[23040];   // 2 x 11520 stage | 16384 transpose
    int tid = threadIdx.x;
    int lane = tid & 63;
    int wv = tid >> 6;
    int wm = wv & 1;       // co half
    int wn = wv >> 1;      // px x-half
    int lm = lane & 15, lk = lane >> 4;
    int tilesX = W >> 4;
    int T = tilesX * (H >> 3);
    // ---- bijective XCD-sample swizzle: pin each sample to 8/g XCDs ----
    int lin = blockIdx.y * T + blockIdx.x;
    int spx = 8 / g;                      // g in {1,2,4,8}
    int zb, tidx;
    if ((T & (spx - 1)) == 0) {
        zb = (lin & 7) / spx;
        tidx = (lin >> 3) * spx + (lin & (spx - 1));
    } else { zb = blockIdx.y; tidx = blockIdx.x; }
    int tx0 = (tidx % tilesX) << 4;
    int ty0 = (tidx / tilesX) << 3;
    int b = b0 + zb;

    float4v acc[4][4];
    #pragma unroll
    for (int mf = 0; mf < 4; ++mf)
        #pragma unroll
        for (int nf = 0; nf < 4; ++nf)
            acc[mf][nf] = (float4v){0.f, 0.f, 0.f, 0.f};

    const ushortT* wB = wF + (size_t)b * (9 * 4 * 4096);

    // ---- staging descriptors: halo 18x10 = 180 px, 720 16B chunks, 3 rounds
    // lds slot d at px holds source slot d ^ m(px), m(px)=(px&3)^((px>>2)&3)
    int goff0 = -1, goff1 = -1, goff2 = -1;
    int loff0 = -1, loff1 = -1, loff2 = -1;
    int u00[3], u01[3], u10[3], u11[3];
    float uwy[3], uwx[3];
    const char* xbase;
    if (!UP2) {
        xbase = (const char*)(xp + (size_t)zb * H * W * 128);
        #pragma unroll
        for (int k = 0; k < 3; ++k) {
            int c = tid + k * 256;
            if (c < 720) {
                int px = c >> 2;
                int hy = px / 18, hx = px - hy * 18;
                int gy = ty0 + hy - 1, gx = tx0 + hx - 1;
                int m = (px & 3) ^ ((px >> 2) & 3);
                int sl = (c & 3) ^ m;
                int lo = px * 64 + (c & 3) * 16;
                int go = ((unsigned)gy < (unsigned)H && (unsigned)gx < (unsigned)W)
                         ? ((gy * W + gx) * 256 + sl * 16) : -1;
                if (k == 0) { goff0 = go; loff0 = lo; }
                else if (k == 1) { goff1 = go; loff1 = lo; }
                else { goff2 = go; loff2 = lo; }
            }
        }
    } else {
        int h2 = H >> 1, w2 = W >> 1;
        xbase = (const char*)(xp + (size_t)zb * h2 * w2 * 128);
        #pragma unroll
        for (int k = 0; k < 3; ++k) {
            u00[k] = -1;
            int c = tid + k * 256;
            if (c < 720) {
                int px = c >> 2;
                int hy = px / 18, hx = px - hy * 18;
                int gy = ty0 + hy - 1, gx = tx0 + hx - 1;
                int m = (px & 3) ^ ((px >> 2) & 3);
                int sl = (c & 3) ^ m;
                int lo = px * 64 + (c & 3) * 16;
                if (k == 0) loff0 = lo; else if (k == 1) loff1 = lo; else loff2 = lo;
                if ((unsigned)gy < (unsigned)H && (unsigned)gx < (unsigned)W) {
                    int y0 = (gy >> 1) - 1 + (gy & 1);
                    uwy[k] = (gy & 1) ? 0.75f : 0.25f;
                    int x0 = (gx >> 1) - 1 + (gx & 1);
                    uwx[k] = (gx & 1) ? 0.75f : 0.25f;
                    int y1 = min(y0 + 1, h2 - 1); y0 = max(y0, 0);
                    int x1 = min(x0 + 1, w2 - 1); x0 = max(x0, 0);
                    u00[k] = (y0 * w2 + x0) * 256 + sl * 16;
                    u01[k] = (y0 * w2 + x1) * 256 + sl * 16;
                    u10[k] = (y1 * w2 + x0) * 256 + sl * 16;
                    u11[k] = (y1 * w2 + x1) * 256 + sl * 16;
                }
            }
        }
    }

    uint4v pf0 = {0,0,0,0}, pf1 = {0,0,0,0}, pf2 = {0,0,0,0};
    const uint4v zv = {0, 0, 0, 0};

    #define PFETCH(q) do { \
        if (!UP2) { \
            pf0 = (goff0 >= 0) ? *(const uint4v*)(xbase + goff0 + (q) * 64) : zv; \
            pf1 = (goff1 >= 0) ? *(const uint4v*)(xbase + goff1 + (q) * 64) : zv; \
            pf2 = (goff2 >= 0) ? *(const uint4v*)(xbase + goff2 + (q) * 64) : zv; \
        } else { \
            uint4v* pfp[3] = {&pf0, &pf1, &pf2}; \
            _Pragma("unroll") \
            for (int k = 0; k < 3; ++k) { \
                uint4v r = zv; \
                if (u00[k] >= 0) { \
                    ushort8v v00 = *(const ushort8v*)(xbase + u00[k] + (q) * 64); \
                    ushort8v v01 = *(const ushort8v*)(xbase + u01[k] + (q) * 64); \
                    ushort8v v10 = *(const ushort8v*)(xbase + u10[k] + (q) * 64); \
                    ushort8v v11 = *(const ushort8v*)(xbase + u11[k] + (q) * 64); \
                    float wy0 = uwy[k], wx0 = uwx[k]; \
                    float wy1 = 1.f - wy0, wx1 = 1.f - wx0; \
                    ushort8v o; \
                    _Pragma("unroll") \
                    for (int e = 0; e < 8; ++e) { \
                        float v = wy0 * (wx0 * bf2f(v00[e]) + wx1 * bf2f(v01[e])) \
                                + wy1 * (wx0 * bf2f(v10[e]) + wx1 * bf2f(v11[e])); \
                        o[e] = f2bf(v); \
                    } \
                    r = __builtin_bit_cast(uint4v, o); \
                } \
                *pfp[k] = r; \
            } \
        } \
    } while (0)

    PFETCH(0);

    for (int q = 0; q < 4; ++q) {
        char* buf = lb + (q & 1) * 11520;
        if (loff0 >= 0) *(uint4v*)(buf + loff0) = pf0;
        if (loff1 >= 0) *(uint4v*)(buf + loff1) = pf1;
        if (loff2 >= 0) *(uint4v*)(buf + loff2) = pf2;
        if (q < 3) {
            if (q == 0) PFETCH(1);
            else if (q == 1) PFETCH(2);
            else PFETCH(3);
        }
        __syncthreads();
        #pragma unroll
        for (int tap = 0; tap < 9; ++tap) {
            const int dy = (tap < 3) ? 0 : (tap < 6 ? 1 : 2);
            const int dx = tap - dy * 3;
            const ushortT* ap = wB + ((tap * 4 + q) << 12) + wm * 2048 + lane * 8;
            short8v a0 = *(const short8v*)(ap);
            short8v a1 = *(const short8v*)(ap + 512);
            short8v a2 = *(const short8v*)(ap + 1024);
            short8v a3 = *(const short8v*)(ap + 1536);
            #pragma unroll
            for (int nf = 0; nf < 4; ++nf) {
                int hy = nf * 2 + (lm >> 3) + dy;
                int hx = wn * 8 + (lm & 7) + dx;
                int hp = hy * 18 + hx;
                int mm = (hp & 3) ^ ((hp >> 2) & 3);
                short8v bf = *(const short8v*)(buf + hp * 64 + ((lk ^ mm) << 4));
                acc[0][nf] = __builtin_amdgcn_mfma_f32_16x16x32_bf16(a0, bf, acc[0][nf], 0, 0, 0);
                acc[1][nf] = __builtin_amdgcn_mfma_f32_16x16x32_bf16(a1, bf, acc[1][nf], 0, 0, 0);
                acc[2][nf] = __builtin_amdgcn_mfma_f32_16x16x32_bf16(a2, bf, acc[2][nf], 0, 0, 0);
                acc[3][nf] = __builtin_amdgcn_mfma_f32_16x16x32_bf16(a3, bf, acc[3][nf], 0, 0, 0);
            }
        }
        __syncthreads();
    }

    // ---------------- epilogue ----------------
    float sn = sn_ptr[0];
    float nv[4];
    #pragma unroll
    for (int nf = 0; nf < 4; ++nf) {
        int gy = ty0 + nf * 2 + (lm >> 3);
        int gx = tx0 + wn * 8 + (lm & 7);
        nv[nf] = sn * nz[((size_t)b * H + gy) * W + gx];
    }
    const float cl2 = 0.08838834764831845f; // 1/sqrt(128)
    float rgbs[4] = {0.f, 0.f, 0.f, 0.f};
    unsigned pka[4][4][2]; // [mf][nf] packed bf16 (co0..co0+3)
    #pragma unroll
    for (int mf = 0; mf < 4; ++mf) {
        int co0 = wm * 64 + mf * 16 + lk * 4;
        float4v dd = *(const float4v*)(d_b + b * 128 + co0);
        float4v bb = *(const float4v*)(bias + co0);
        float4v cf = {0.f, 0.f, 0.f, 0.f};
        if (do_rgb) {
            float4v rw = *(const float4v*)(rgbw_i + co0);
            float4v sv = *(const float4v*)(s_blk + b * 128 + co0);
            #pragma unroll
            for (int e = 0; e < 4; ++e) cf[e] = rw[e] * cl2 * sv[e];
        }
        #pragma unroll
        for (int nf = 0; nf < 4; ++nf) {
            float v[4];
            #pragma unroll
            for (int e = 0; e < 4; ++e) {
                float t = acc[mf][nf][e] * dd[e] + nv[nf] + bb[e];
                v[e] = t > 0.f ? t : 0.2f * t;
            }
            if (do_rgb)
                rgbs[nf] += v[0] * cf[0] + v[1] * cf[1] + v[2] * cf[2] + v[3] * cf[3];
            pka[mf][nf][0] = (unsigned)f2bf(v[0]) | ((unsigned)f2bf(v[1]) << 16);
            pka[mf][nf][1] = (unsigned)f2bf(v[2]) | ((unsigned)f2bf(v[3]) << 16);
        }
    }
    if (do_rgb) {
        #pragma unroll
        for (int nf = 0; nf < 4; ++nf) {
            float r = rgbs[nf];
            r += __shfl_xor(r, 16, 64);
            r += __shfl_xor(r, 32, 64);
            if (lane < 16) {
                int gy = ty0 + nf * 2 + (lane >> 3);
                int gx = tx0 + wn * 8 + (lane & 7);
                rgbb[((size_t)(wm * BATCH + b) * H + gy) * W + gx] = r;
            }
        }
    }
    // two co-half transpose rounds (16 KB each); contiguous 8B per (mf,nf)
    char* xb2 = (char*)(yp + (size_t)zb * H * W * 128);
    #pragma unroll
    for (int h = 0; h < 2; ++h) {
        if (wm == h) {
            #pragma unroll
            for (int mf = 0; mf < 4; ++mf) {
                int cb = (mf * 16 + lk * 4) * 2; // local co byte, 8-aligned
                #pragma unroll
                for (int nf = 0; nf < 4; ++nf) {
                    int pxl = (nf * 2 + (lm >> 3)) * 16 + wn * 8 + (lm & 7);
                    int ad = pxl * 128 + (cb ^ ((pxl & 7) << 4));
                    uint2v pk2;
                    pk2[0] = pka[mf][nf][0];
                    pk2[1] = pka[mf][nf][1];
                    *(uint2v*)(lb + ad) = pk2;
                }
            }
        }
        __syncthreads();
        for (int c = tid; c < 1024; c += 256) {
            int pxl = c >> 3, ck = c & 7;
            uint4v v = *(const uint4v*)(lb + pxl * 128 + ((ck << 4) ^ ((pxl & 7) << 4)));
            int gy = ty0 + (pxl >> 4), gx = tx0 + (pxl & 15);
            *(uint4v*)(xb2 + ((size_t)(gy * W + gx)) * 256 + h * 128 + ck * 16) = v;
        }
        if (h == 0) __syncthreads();
    }
    #undef PFETCH
}

// ---------------- bilinear upsample rgb (r->256), sum 2 partial planes
__global__ void k_rgbacc(const float* __restrict__ rgb, float* __restrict__ acc,
                         int r, int beta, int b0, int g) {
    int idx = blockIdx.x * blockDim.x + threadIdx.x;
    if (idx >= g * 256 * 256) return;
    int ox = idx & 255;
    int oy = (idx >> 8) & 255;
    int b = b0 + (idx >> 16);
    float scale = (float)r * (1.0f / 256.0f);
    float fy = (oy + 0.5f) * scale - 0.5f;
    float fx = (ox + 0.5f) * scale - 0.5f;
    int y0 = (int)floorf(fy); float wy = fy - (float)y0;
    int x0 = (int)floorf(fx); float wx = fx - (float)x0;
    int y1 = min(y0 + 1, r - 1); y0 = max(y0, 0);
    int x1 = min(x0 + 1, r - 1); x0 = max(x0, 0);
    const float* p0 = rgb + (size_t)b * r * r;
    const float* p1 = rgb + (size_t)(BATCH + b) * r * r;
    float v00 = p0[y0 * r + x0] + p1[y0 * r + x0];
    float v01 = p0[y0 * r + x1] + p1[y0 * r + x1];
    float v10 = p0[y1 * r + x0] + p1[y1 * r + x0];
    float v11 = p0[y1 * r + x1] + p1[y1 * r + x1];
    float v = (1.f - wy) * ((1.f - wx) * v00 + wx * v01)
            +        wy  * ((1.f - wx) * v10 + wx * v11);
    int oidx = (b << 16) | (oy << 8) | ox;
    acc[oidx] = (beta ? acc[oidx] : 0.f) + v;
}

__global__ void k_final(float* __restrict__ out, int total) {
    int idx = blockIdx.x * blockDim.x + threadIdx.x;
    if (idx < total) out[idx] = out[idx] * 0.5f + 0.5f;
}

extern "C" void kernel_launch(void* const* d_in, const int* in_sizes, int n_in,
                              void* d_out, int out_size, void* d_ws, size_t ws_size,
                              hipStream_t stream) {
    const float* w     = (const float*)d_in[0];
    const float* noise[4] = {(const float*)d_in[1], (const float*)d_in[2],
                             (const float*)d_in[3], (const float*)d_in[4]};
    const float* ic    = (const float*)d_in[5];
    const float* tsw   = (const float*)d_in[6];
    const float* tsb   = (const float*)d_in[7];
    const float* cw    = (const float*)d_in[8];
    const float* snp   = (const float*)d_in[9];
    const float* sbias = (const float*)d_in[10];
    const float* rgbw  = (const float*)d_in[11];

    // ws: s(16K) d(32K) rgbb(4M, 2 planes) Wm(18.87M) bufA bufB ; acc = d_out
    const size_t WM_BYTES = 8ull * 8 * 9 * 4 * 8 * 64 * 8 * 2; // 18,874,368
    const size_t RGBB = 2ull * BATCH * 65536 * 4;              // 4,194,304
    const size_t FIXED = 16384 + 32768 + RGBB + WM_BYTES;      // 23,117,824
    const size_t PER_S = 65536ull * 128 * 2;                   // 16,777,216
    int g = 0;
    for (int cand = 8; cand >= 1; cand >>= 1)
        if (ws_size >= FIXED + 2ull * cand * PER_S) { g = cand; break; }
    if (g == 0) return;

    char* ws = (char*)d_ws;
    float* s_all   = (float*)ws;
    float* d_all   = (float*)(ws + 16384);
    float* rgbb    = (float*)(ws + 49152);
    ushortT* wmall = (ushortT*)(ws + 49152 + RGBB);
    ushortT* bufA  = (ushortT*)(ws + FIXED);
    ushortT* bufB  = (ushortT*)(ws + FIXED + (size_t)g * PER_S);
    float* accb    = (float*)d_out;

    k_style<<<64, 64, 0, stream>>>(w, tsw, tsb, s_all);
    k_demod<<<1024, 64, 0, stream>>>(cw, s_all, d_all);
    k_wmodF<<<4608, 256, 0, stream>>>(cw, s_all, wmall);

    for (int b0 = 0; b0 < BATCH; b0 += g) {
        ushortT* xb = bufA;
        ushortT* tb = bufB;
        int t0 = g * 1024 * 128;
        k_prep_init<<<(t0 + 255) / 256, 256, 0, stream>>>(ic, xb, t0);
        for (int i = 0; i < NB; ++i) {
            int r = 32 << i;
            const float* s_i = s_all + i * BATCH * NF;
            for (int j = 0; j < 2; ++j) {
                int l = i * 2 + j;
                const ushortT* wl = wmall + (size_t)l * (8 * 9 * 4 * 4096);
                const float* dl = d_all + l * BATCH * NF;
                const float* nzp = noise[i] + (size_t)j * BATCH * r * r;
                const float* bs = sbias + l * NF;
                int dorgb = (j == 1) ? 1 : 0;
                dim3 grid((r / 16) * (r / 8), g);
                if (i > 0 && j == 0)
                    k_conv4<1><<<grid, 256, 0, stream>>>(xb, tb, wl, dl, nzp, bs,
                        snp + l, s_i, rgbw + i * NF, rgbb, r, r, b0, g, dorgb);
                else
                    k_conv4<0><<<grid, 256, 0, stream>>>(xb, tb, wl, dl, nzp, bs,
                        snp + l, s_i, rgbw + i * NF, rgbb, r, r, b0, g, dorgb);
                ushortT* tmp = xb; xb = tb; tb = tmp;
            }
            int tot = g * 256 * 256;
            k_rgbacc<<<(tot + 255) / 256, 256, 0, stream>>>(rgbb, accb, r, i, b0, g);
        }
    }
    k_final<<<(out_size + 255) / 256, 256, 0, stream>>>(accb, out_size);
}

// Round 8
// 1014.261 us; speedup vs baseline: 28.4390x; 1.1636x over previous
//
#include <hip/hip_runtime.h>
#include <math.h>

#define NB 4
#define BATCH 8
#define NF 128
#define WDIM 512
#define EPS_D 1e-8f

typedef unsigned short ushortT;
typedef __attribute__((ext_vector_type(8))) short short8v;
typedef __attribute__((ext_vector_type(8))) unsigned short ushort8v;
typedef __attribute__((ext_vector_type(4))) float float4v;
typedef __attribute__((ext_vector_type(4))) unsigned int uint4v;
typedef __attribute__((ext_vector_type(2))) unsigned int uint2v;

__device__ inline unsigned short f2bf(float f) {
    unsigned u = __builtin_bit_cast(unsigned, f);
    u = (u + 0x7fffu + ((u >> 16) & 1u)) >> 16;
    return (unsigned short)u;
}
__device__ inline float bf2f(unsigned short h) {
    unsigned u = ((unsigned)h) << 16;
    return __builtin_bit_cast(float, u);
}

// ---------------- style
__global__ void k_style(const float* __restrict__ w,
                        const float* __restrict__ tsw,
                        const float* __restrict__ tsb,
                        float* __restrict__ s) {
    int gid = blockIdx.x * blockDim.x + threadIdx.x;
    if (gid >= NB * BATCH * NF) return;
    int i = gid >> 10;
    int b = (gid >> 7) & 7;
    int o = gid & 127;
    const float cl = 0.044194173824159216f; // 1/sqrt(512)
    const float* wr = w + (i * BATCH + b) * WDIM;
    const float* tr = tsw + (i * NF + o) * WDIM;
    float acc = 0.f;
    for (int k = 0; k < WDIM; ++k) acc += wr[k] * tr[k];
    s[gid] = acc * cl + tsb[i * NF + o];
}

// ---------------- demod (f32 exact)
__global__ void k_demod(const float* __restrict__ conv_w,
                        const float* __restrict__ s,
                        float* __restrict__ d) {
    int bx = blockIdx.x; // l*128 + o
    int l = bx >> 7;
    int o = bx & 127;
    int lane = threadIdx.x;
    const float* wb = conv_w + (size_t)((l * NF + o) * NF) * 9;
    float t0 = 0.f, t1 = 0.f;
    for (int k = 0; k < 9; ++k) {
        float a = wb[lane * 9 + k];        t0 += a * a;
        float c = wb[(lane + 64) * 9 + k]; t1 += c * c;
    }
    const float c2 = 1.0f / 1152.0f;
    int i = l >> 1;
    for (int b = 0; b < BATCH; ++b) {
        float s0 = s[(i * BATCH + b) * NF + lane];
        float s1 = s[(i * BATCH + b) * NF + lane + 64];
        float v = t0 * s0 * s0 + t1 * s1 * s1;
        for (int off = 32; off > 0; off >>= 1) v += __shfl_down(v, off);
        if (lane == 0) d[(l * BATCH + b) * NF + o] = rsqrtf(v * c2 + EPS_D);
    }
}

// ---------------- fragment-major modulated weights
// wmF[l][b][tap][kcc(4)][mf(8)][lane(64)][e(8)] bf16; lane = lk*16+lm
__global__ void k_wmodF(const float* __restrict__ cw, const float* __restrict__ s,
                        ushortT* __restrict__ wm) {
    int idx = blockIdx.x * blockDim.x + threadIdx.x; // 1,179,648
    int lane = idx & 63;
    int mf = (idx >> 6) & 7;
    int kcc = (idx >> 9) & 3;
    int t = (idx >> 11) % 9;
    int r2 = idx / (2048 * 9);
    int b = r2 & 7;
    int l = r2 >> 3;
    if (l >= 8) return;
    const float cscale = 0.029462782549439483f; // 1/sqrt(1152)
    int co = mf * 16 + (lane & 15);
    int kb = kcc * 32 + (lane >> 4) * 8;
    const float* src = cw + (((size_t)l * NF + co) * NF) * 9;
    const float* sr = s + ((l >> 1) * BATCH + b) * NF;
    ushort8v o;
    #pragma unroll
    for (int e = 0; e < 8; ++e) {
        int ci = kb + e;
        o[e] = f2bf(src[(size_t)ci * 9 + t] * cscale * sr[ci]);
    }
    *(ushort8v*)(wm + (size_t)idx * 8) = o;
}

// ---------------- initial constant -> relu -> bf16 NHWC (g samples)
__global__ void k_prep_init(const float* __restrict__ ic, ushortT* __restrict__ xp,
                            int total) {
    for (int idx = blockIdx.x * blockDim.x + threadIdx.x; idx < total;
         idx += gridDim.x * blockDim.x) {
        int ci = idx & 127;
        int p = (idx >> 7) & 1023;
        float v = ic[ci * 1024 + p];
        xp[idx] = f2bf(v > 0.f ? v : 0.f);
    }
}

// ---------------- 2x bilinear upsample, bf16 NHWC (standalone, R3-verified)
__global__ void k_up2_bf(const ushortT* __restrict__ in, ushortT* __restrict__ out,
                         int h, int w, int total) {
    int W2 = w * 2, H2 = h * 2;
    for (int gid = blockIdx.x * blockDim.x + threadIdx.x; gid < total;
         gid += gridDim.x * blockDim.x) {
        int cg = gid & 15;
        int t = gid >> 4;
        int ox = t % W2; t /= W2;
        int oy = t % H2; int zb = t / H2;
        int y0 = (oy >> 1) - 1 + (oy & 1);
        float wy0 = (oy & 1) ? 0.75f : 0.25f;
        int x0 = (ox >> 1) - 1 + (ox & 1);
        float wx0 = (ox & 1) ? 0.75f : 0.25f;
        int y1 = min(y0 + 1, h - 1); y0 = max(y0, 0);
        int x1 = min(x0 + 1, w - 1); x0 = max(x0, 0);
        const ushortT* base = in + (size_t)zb * h * w * 128 + cg * 8;
        ushort8v v00 = *(const ushort8v*)(base + (size_t)(y0 * w + x0) * 128);
        ushort8v v01 = *(const ushort8v*)(base + (size_t)(y0 * w + x1) * 128);
        ushort8v v10 = *(const ushort8v*)(base + (size_t)(y1 * w + x0) * 128);
        ushort8v v11 = *(const ushort8v*)(base + (size_t)(y1 * w + x1) * 128);
        float wy1 = 1.f - wy0, wx1 = 1.f - wx0;
        ushort8v o;
        #pragma unroll
        for (int k = 0; k < 8; ++k) {
            float v = wy0 * (wx0 * bf2f(v00[k]) + wx1 * bf2f(v01[k]))
                    + wy1 * (wx0 * bf2f(v10[k]) + wx1 * bf2f(v11[k]));
            o[k] = f2bf(v);
        }
        *(ushort8v*)(out + ((size_t)(zb * H2 + oy) * W2 + ox) * 128 + cg * 8) = o;
    }
}

// ============ fused conv: modconv3x3 + demod + noise + bias + leaky + [ToRGB]
// 16(w)x8(h) px tile, 256 thr (4 waves); wave = 64co (wm) x 64px (wn x-half).
// ci in 2 halves of 64; staging via global_load_lds (linear LDS dest,
// pre-swizzled global source: slot^ (px&7) over 128B rows -> 2-way-free reads).
__global__ __launch_bounds__(256, 3) void k_conv5(
    const ushortT* __restrict__ xp, ushortT* __restrict__ yp,
    const ushortT* __restrict__ wF,   // [8b][9][4][8][64][8]
    const float* __restrict__ d_b,    // [8][128]
    const float* __restrict__ nz,     // [8][H][W]
    const float* __restrict__ bias,   // [128]
    const float* __restrict__ sn_ptr,
    const float* __restrict__ s_blk,  // [8][128]
    const float* __restrict__ rgbw_i, // [128]
    float* __restrict__ rgbb,         // [2][8][H][W] f32 partials
    int H, int W, int b0, int do_rgb)
{
    __shared__ __align__(16) char lb[46080];   // 2 x 23040 (halo 180px x 128B)
    int tid = threadIdx.x;
    int lane = tid & 63;
    int wv = tid >> 6;
    int wm = wv & 1;       // co half
    int wn = wv >> 1;      // px x-half
    int lm = lane & 15, lk = lane >> 4;
    int tilesX = W >> 4;
    int tx0 = (blockIdx.x % tilesX) << 4;
    int ty0 = (blockIdx.x / tilesX) << 3;
    int zb = blockIdx.y;
    int b = b0 + zb;
    const char* xbase = (const char*)(xp + (size_t)zb * H * W * 128);

    // per-lane stage source offsets for 6 issue rounds (chunk = wv*360+it*64+lane)
    int offs[6];
    #pragma unroll
    for (int it = 0; it < 6; ++it) {
        int cw = it * 64 + lane;
        int off = -1;
        if (cw < 360) {
            int chunk = wv * 360 + cw;
            int px = chunk >> 3, slot = chunk & 7;
            int hy = px / 18, hx = px - hy * 18;
            int gy = ty0 + hy - 1, gx = tx0 + hx - 1;
            if ((unsigned)gy < (unsigned)H && (unsigned)gx < (unsigned)W)
                off = (gy * W + gx) * 256 + ((slot ^ (px & 7)) << 4);
        }
        offs[it] = off;
    }

    // zero both buffers (covers halo-border slots skipped by masked loads)
    {
        const uint4v zv = {0, 0, 0, 0};
        #pragma unroll
        for (int c = 0; c < 12; ++c) {
            int idx = tid + c * 256;
            if (idx < 2880) *(uint4v*)(lb + idx * 16) = zv;
        }
    }
    __syncthreads();

    #define ISSUE(cih) do { \
        char* dst0 = lb + (cih) * 23040 + wv * 5760; \
        _Pragma("unroll") \
        for (int it = 0; it < 6; ++it) { \
            if (offs[it] >= 0) \
                __builtin_amdgcn_global_load_lds( \
                    (const __attribute__((address_space(1))) void*)(xbase + offs[it] + (cih) * 128), \
                    (__attribute__((address_space(3))) void*)(dst0 + it * 1024), 16, 0, 0); \
        } \
    } while (0)

    ISSUE(0);
    __syncthreads();          // half0 staged
    ISSUE(1);                 // half1 loads fly during half0 compute

    float4v acc[4][4];
    #pragma unroll
    for (int mf = 0; mf < 4; ++mf)
        #pragma unroll
        for (int nf = 0; nf < 4; ++nf)
            acc[mf][nf] = (float4v){0.f, 0.f, 0.f, 0.f};

    const ushortT* wB = wF + (size_t)b * (9 * 4 * 4096);

    for (int cih = 0; cih < 2; ++cih) {
        if (cih) __syncthreads();   // half1 staged
        const char* buf = lb + cih * 23040;
        #pragma unroll
        for (int tap = 0; tap < 9; ++tap) {
            const int dy = (tap < 3) ? 0 : (tap < 6 ? 1 : 2);
            const int dx = tap - dy * 3;
            #pragma unroll
            for (int kc = 0; kc < 2; ++kc) {
                const ushortT* ap = wB + ((size_t)(tap * 4 + cih * 2 + kc) << 12)
                                    + wm * 2048 + lane * 8;
                short8v a0 = *(const short8v*)(ap);
                short8v a1 = *(const short8v*)(ap + 512);
                short8v a2 = *(const short8v*)(ap + 1024);
                short8v a3 = *(const short8v*)(ap + 1536);
                #pragma unroll
                for (int nf = 0; nf < 4; ++nf) {
                    int row = nf * 2 + (lm >> 3) + dy;
                    int col = wn * 8 + (lm & 7) + dx;
                    int hp = row * 18 + col;
                    short8v bf = *(const short8v*)(buf + hp * 128
                                 + ((((kc << 2) + lk) ^ (hp & 7)) << 4));
                    acc[0][nf] = __builtin_amdgcn_mfma_f32_16x16x32_bf16(a0, bf, acc[0][nf], 0, 0, 0);
                    acc[1][nf] = __builtin_amdgcn_mfma_f32_16x16x32_bf16(a1, bf, acc[1][nf], 0, 0, 0);
                    acc[2][nf] = __builtin_amdgcn_mfma_f32_16x16x32_bf16(a2, bf, acc[2][nf], 0, 0, 0);
                    acc[3][nf] = __builtin_amdgcn_mfma_f32_16x16x32_bf16(a3, bf, acc[3][nf], 0, 0, 0);
                }
            }
        }
    }
    __syncthreads();   // all halo reads done; reuse lb for output transpose

    // ---------------- epilogue ----------------
    float sn = sn_ptr[0];
    float nv[4];
    #pragma unroll
    for (int nf = 0; nf < 4; ++nf) {
        int gy = ty0 + nf * 2 + (lm >> 3);
        int gx = tx0 + wn * 8 + (lm & 7);
        nv[nf] = sn * nz[((size_t)b * H + gy) * W + gx];
    }
    const float cl2 = 0.08838834764831845f; // 1/sqrt(128)
    float rgbs[4] = {0.f, 0.f, 0.f, 0.f};
    unsigned pka[4][4][2]; // [mf][nf] packed bf16 (co0..co0+3)
    #pragma unroll
    for (int mf = 0; mf < 4; ++mf) {
        int co0 = wm * 64 + mf * 16 + lk * 4;
        float4v dd = *(const float4v*)(d_b + b * 128 + co0);
        float4v bb = *(const float4v*)(bias + co0);
        float4v cf = {0.f, 0.f, 0.f, 0.f};
        if (do_rgb) {
            float4v rw = *(const float4v*)(rgbw_i + co0);
            float4v sv = *(const float4v*)(s_blk + b * 128 + co0);
            #pragma unroll
            for (int e = 0; e < 4; ++e) cf[e] = rw[e] * cl2 * sv[e];
        }
        #pragma unroll
        for (int nf = 0; nf < 4; ++nf) {
            float v[4];
            #pragma unroll
            for (int e = 0; e < 4; ++e) {
                float t = acc[mf][nf][e] * dd[e] + nv[nf] + bb[e];
                v[e] = t > 0.f ? t : 0.2f * t;
            }
            if (do_rgb)
                rgbs[nf] += v[0] * cf[0] + v[1] * cf[1] + v[2] * cf[2] + v[3] * cf[3];
            pka[mf][nf][0] = (unsigned)f2bf(v[0]) | ((unsigned)f2bf(v[1]) << 16);
            pka[mf][nf][1] = (unsigned)f2bf(v[2]) | ((unsigned)f2bf(v[3]) << 16);
        }
    }
    if (do_rgb) {
        #pragma unroll
        for (int nf = 0; nf < 4; ++nf) {
            float r = rgbs[nf];
            r += __shfl_xor(r, 16, 64);
            r += __shfl_xor(r, 32, 64);
            if (lane < 16) {
                int gy = ty0 + nf * 2 + (lane >> 3);
                int gx = tx0 + wn * 8 + (lane & 7);
                rgbb[((size_t)(wm * BATCH + b) * H + gy) * W + gx] = r;
            }
        }
    }
    // two co-half transpose rounds (16 KB each); contiguous 8B per (mf,nf)
    char* xb2 = (char*)(yp + (size_t)zb * H * W * 128);
    #pragma unroll
    for (int h = 0; h < 2; ++h) {
        if (wm == h) {
            #pragma unroll
            for (int mf = 0; mf < 4; ++mf) {
                int cb = (mf * 16 + lk * 4) * 2; // local co byte, 8-aligned
                #pragma unroll
                for (int nf = 0; nf < 4; ++nf) {
                    int pxl = (nf * 2 + (lm >> 3)) * 16 + wn * 8 + (lm & 7);
                    int ad = pxl * 128 + (cb ^ ((pxl & 7) << 4));
                    uint2v pk2;
                    pk2[0] = pka[mf][nf][0];
                    pk2[1] = pka[mf][nf][1];
                    *(uint2v*)(lb + ad) = pk2;
                }
            }
        }
        __syncthreads();
        for (int c = tid; c < 1024; c += 256) {
            int pxl = c >> 3, ck = c & 7;
            uint4v v = *(const uint4v*)(lb + pxl * 128 + ((ck << 4) ^ ((pxl & 7) << 4)));
            int gy = ty0 + (pxl >> 4), gx = tx0 + (pxl & 15);
            *(uint4v*)(xb2 + ((size_t)(gy * W + gx)) * 256 + h * 128 + ck * 16) = v;
        }
        if (h == 0) __syncthreads();
    }
    #undef ISSUE
}

// ---------------- bilinear upsample rgb (r->256), sum 2 partial planes
__global__ void k_rgbacc(const float* __restrict__ rgb, float* __restrict__ acc,
                         int r, int beta, int b0, int g) {
    int idx = blockIdx.x * blockDim.x + threadIdx.x;
    if (idx >= g * 256 * 256) return;
    int ox = idx & 255;
    int oy = (idx >> 8) & 255;
    int b = b0 + (idx >> 16);
    float scale = (float)r * (1.0f / 256.0f);
    float fy = (oy + 0.5f) * scale - 0.5f;
    float fx = (ox + 0.5f) * scale - 0.5f;
    int y0 = (int)floorf(fy); float wy = fy - (float)y0;
    int x0 = (int)floorf(fx); float wx = fx - (float)x0;
    int y1 = min(y0 + 1, r - 1); y0 = max(y0, 0);
    int x1 = min(x0 + 1, r - 1); x0 = max(x0, 0);
    const float* p0 = rgb + (size_t)b * r * r;
    const float* p1 = rgb + (size_t)(BATCH + b) * r * r;
    float v00 = p0[y0 * r + x0] + p1[y0 * r + x0];
    float v01 = p0[y0 * r + x1] + p1[y0 * r + x1];
    float v10 = p0[y1 * r + x0] + p1[y1 * r + x0];
    float v11 = p0[y1 * r + x1] + p1[y1 * r + x1];
    float v = (1.f - wy) * ((1.f - wx) * v00 + wx * v01)
            +        wy  * ((1.f - wx) * v10 + wx * v11);
    int oidx = (b << 16) | (oy << 8) | ox;
    acc[oidx] = (beta ? acc[oidx] : 0.f) + v;
}

__global__ void k_final(float* __restrict__ out, int total) {
    int idx = blockIdx.x * blockDim.x + threadIdx.x;
    if (idx < total) out[idx] = out[idx] * 0.5f + 0.5f;
}

extern "C" void kernel_launch(void* const* d_in, const int* in_sizes, int n_in,
                              void* d_out, int out_size, void* d_ws, size_t ws_size,
                              hipStream_t stream) {
    const float* w     = (const float*)d_in[0];
    const float* noise[4] = {(const float*)d_in[1], (const float*)d_in[2],
                             (const float*)d_in[3], (const float*)d_in[4]};
    const float* ic    = (const float*)d_in[5];
    const float* tsw   = (const float*)d_in[6];
    const float* tsb   = (const float*)d_in[7];
    const float* cw    = (const float*)d_in[8];
    const float* snp   = (const float*)d_in[9];
    const float* sbias = (const float*)d_in[10];
    const float* rgbw  = (const float*)d_in[11];

    // ws: s(16K) d(32K) rgbb(4M, 2 planes) Wm(18.87M) bufA bufB ; acc = d_out
    const size_t WM_BYTES = 8ull * 8 * 9 * 4 * 8 * 64 * 8 * 2; // 18,874,368
    const size_t RGBB = 2ull * BATCH * 65536 * 4;              // 4,194,304
    const size_t FIXED = 16384 + 32768 + RGBB + WM_BYTES;      // 23,117,824
    const size_t PER_S = 65536ull * 128 * 2;                   // 16,777,216
    int g = 0;
    for (int cand = 8; cand >= 1; cand >>= 1)
        if (ws_size >= FIXED + 2ull * cand * PER_S) { g = cand; break; }
    if (g == 0) return;

    char* ws = (char*)d_ws;
    float* s_all   = (float*)ws;
    float* d_all   = (float*)(ws + 16384);
    float* rgbb    = (float*)(ws + 49152);
    ushortT* wmall = (ushortT*)(ws + 49152 + RGBB);
    ushortT* bufA  = (ushortT*)(ws + FIXED);
    ushortT* bufB  = (ushortT*)(ws + FIXED + (size_t)g * PER_S);
    float* accb    = (float*)d_out;

    k_style<<<64, 64, 0, stream>>>(w, tsw, tsb, s_all);
    k_demod<<<1024, 64, 0, stream>>>(cw, s_all, d_all);
    k_wmodF<<<4608, 256, 0, stream>>>(cw, s_all, wmall);

    for (int b0 = 0; b0 < BATCH; b0 += g) {
        ushortT* xb = bufA;
        ushortT* tb = bufB;
        int t0 = g * 1024 * 128;
        k_prep_init<<<(t0 + 255) / 256, 256, 0, stream>>>(ic, xb, t0);
        for (int i = 0; i < NB; ++i) {
            int r = 32 << i;
            const float* s_i = s_all + i * BATCH * NF;
            if (i > 0) {
                int total = g * r * r * 16;
                int blocks = (total + 255) / 256;
                if (blocks > 2048) blocks = 2048;
                k_up2_bf<<<blocks, 256, 0, stream>>>(xb, tb, r / 2, r / 2, total);
                ushortT* tmp = xb; xb = tb; tb = tmp;
            }
            for (int j = 0; j < 2; ++j) {
                int l = i * 2 + j;
                const ushortT* wl = wmall + (size_t)l * (8 * 9 * 4 * 4096);
                const float* dl = d_all + l * BATCH * NF;
                const float* nzp = noise[i] + (size_t)j * BATCH * r * r;
                const float* bs = sbias + l * NF;
                int dorgb = (j == 1) ? 1 : 0;
                dim3 grid((r / 16) * (r / 8), g);
                k_conv5<<<grid, 256, 0, stream>>>(xb, tb, wl, dl, nzp, bs,
                    snp + l, s_i, rgbw + i * NF, rgbb, r, r, b0, dorgb);
                ushortT* tmp = xb; xb = tb; tb = tmp;
            }
            int tot = g * 256 * 256;
            k_rgbacc<<<(tot + 255) / 256, 256, 0, stream>>>(rgbb, accb, r, i, b0, g);
        }
    }
    k_final<<<(out_size + 255) / 256, 256, 0, stream>>>(accb, out_size);
}